// Round 10
// baseline (433.889 us; speedup 1.0000x reference)
//
#include <hip/hip_runtime.h>
#include <hip/hip_bf16.h>

using s8 = __attribute__((ext_vector_type(8))) short;
using f4 = __attribute__((ext_vector_type(4))) float;
using us8 = __attribute__((ext_vector_type(8))) unsigned short;

__device__ __forceinline__ void glds16(const void* g, void* l) {
    __builtin_amdgcn_global_load_lds(
        (const __attribute__((address_space(1))) void*)g,
        (__attribute__((address_space(3))) void*)l, 16, 0, 0);
}

__device__ __forceinline__ unsigned short f2b(float f) {
    union { float f; unsigned u; } v; v.f = f;
    unsigned r = v.u + 0x7fffu + ((v.u >> 16) & 1u);
    return (unsigned short)(r >> 16);
}
__device__ __forceinline__ float softplus_f(float x) {
    return fmaxf(x, 0.f) + __logf(1.f + __expf(-fabsf(x)));
}
__device__ __forceinline__ float sigmoid_f(float x) {
    return 1.f / (1.f + __expf(-x));
}
__device__ __forceinline__ float exp2_f(float x) {
    float r; asm("v_exp_f32 %0, %1" : "=v"(r) : "v"(x)); return r;
}
__device__ __forceinline__ float log2_f(float x) {
    float r; asm("v_log_f32 %0, %1" : "=v"(r) : "v"(x)); return r;
}

__device__ __forceinline__ float lse12(const float* s) {
    float m = s[0];
#pragma unroll
    for (int j = 1; j < 12; j++) m = fmaxf(m, s[j]);
    float sum = 0.f;
#pragma unroll
    for (int j = 0; j < 12; j++) sum += __expf(s[j] - m);
    return m + __logf(sum);
}

// ---------------------------------------------------------------------------
// prep_all_k: input-only prep (NO Acat — encoder reads se directly now).
//   [0,2752)      6 weight transposes (f32->bf16, zero-padded)
//   [2752,4200)   WcatT (8 x 181 tiles)
//   [4200,5586)   flat misc: pz->pzb | gscale | WhcT
// ---------------------------------------------------------------------------
__global__ __launch_bounds__(256) void prep_all_k(
    const float* __restrict__ cW1, const float* __restrict__ cW2,
    const float* __restrict__ cW3, const float* __restrict__ fW1,
    const float* __restrict__ fW2, const float* __restrict__ fW3,
    unsigned short* __restrict__ cW1T, unsigned short* __restrict__ cW2T,
    unsigned short* __restrict__ cW3T, unsigned short* __restrict__ fW1T,
    unsigned short* __restrict__ fW2T, unsigned short* __restrict__ fW3T,
    const float* __restrict__ Wref, unsigned short* __restrict__ WcatT,
    const float* __restrict__ pz, unsigned short* __restrict__ pzb,
    const float* __restrict__ gb1, const float* __restrict__ gW2,
    float* __restrict__ b1s, float* __restrict__ w2s,
    const float* __restrict__ Wl, const float* __restrict__ Ws,
    const float* __restrict__ Wm, const float* __restrict__ cWl,
    const float* __restrict__ cWs, const float* __restrict__ cWm,
    unsigned short* __restrict__ WhcT) {
    __shared__ float tile[32][33];
    const int b = blockIdx.x, t = threadIdx.x;
    if (b < 2752) {
        int z, r = b;
        if (r < 64) { z = 0; }
        else if (r < 1088) { z = 1; r -= 64; }
        else if (r < 1216) { z = 2; r -= 1088; }
        else if (r < 1472) { z = 3; r -= 1216; }
        else if (r < 2496) { z = 4; r -= 1472; }
        else { z = 5; r -= 2496; }
        const float* src = z == 0 ? cW1 : z == 1 ? cW2 : z == 2 ? cW3
                          : z == 3 ? fW1 : z == 4 ? fW2 : fW3;
        unsigned short* dst = z == 0 ? cW1T : z == 1 ? cW2T : z == 2 ? cW3T
                             : z == 3 ? fW1T : z == 4 ? fW2T : fW3T;
        const int K    = z == 0 ? 64 : z == 3 ? 227 : 1024;
        const int N    = z == 2 ? 64 : z == 5 ? 227 : 1024;
        const int Kpad = z == 0 ? 64 : z == 3 ? 256 : 1024;
        const int Npad = z == 2 ? 128 : z == 5 ? 256 : 1024;
        const int nbx = Npad >> 5;
        const int bx = r % nbx, by = r / nbx;
        const int n0 = bx * 32, k0 = by * 32;
        const int tx = t & 31, ty = t >> 5;
#pragma unroll
        for (int rr = 0; rr < 4; rr++) {
            int k = k0 + ty + rr * 8, n = n0 + tx;
            tile[ty + rr * 8][tx] = (k < K && n < N) ? src[(size_t)k * N + n] : 0.f;
        }
        __syncthreads();
#pragma unroll
        for (int rr = 0; rr < 4; rr++) {
            int n = n0 + ty + rr * 8, k = k0 + tx;
            dst[(size_t)n * Kpad + k] = f2b(tile[tx][ty + rr * 8]);
        }
    } else if (b < 4200) {
        const int r = b - 2752;
        const int n0 = (r & 7) * 32, k0 = (r >> 3) * 32;
        const int tx = t & 31, ty = t >> 5;
#pragma unroll
        for (int rr = 0; rr < 4; rr++) {
            int k = k0 + ty + rr * 8, n = n0 + tx;
            float v = 0.f;
            if (n < 227 && k < 5769) {
                if (k < 5705) {
                    int wrow = k + 64 * (k / 163);
                    v = Wref[(size_t)wrow * 227 + n];
                } else {
                    int j2 = k - 5705;
                    for (int tt = 0; tt < 35; tt++)
                        v += Wref[(size_t)(tt * 227 + 163 + j2) * 227 + n];
                }
            }
            tile[ty + rr * 8][tx] = v;
        }
        __syncthreads();
#pragma unroll
        for (int rr = 0; rr < 4; rr++) {
            int n = n0 + ty + rr * 8, k = k0 + tx;
            if (n < 256 && k < 5792)
                WcatT[(size_t)n * 5792 + k] = f2b(tile[tx][ty + rr * 8]);
        }
    } else {
        constexpr int NCVT = 4096 * 64;
        constexpr int NGS = 227 * 227;
        constexpr int NW = 128 * 320;
        int i = (b - 4200) * 256 + t;
        if (i < NCVT) {
            pzb[i] = f2b(pz[i]);
        } else if (i < NCVT + NGS) {
            int j = i - NCVT;
            b1s[j] = gb1[j] * 1.44269504f;
            w2s[j] = gW2[j] * 0.69314718f;
        } else if (i < NCVT + NGS + NW) {
            int j = i - NCVT - NGS;
            int n = j / 320, k = j - n * 320;
            float v = 0.f;
            if (n < 62 && k < 227) {
                if (n < 25)      v = Wl[(size_t)k * 25 + n];
                else if (n < 37) v = Ws[(size_t)k * 12 + (n - 25)];
                else             v = Wm[(size_t)k * 25 + (n - 37)];
            } else if (n >= 64 && n < 126 && k >= 256) {
                const int jj = n - 64, kk = k - 256;
                if (jj < 25)      v = cWl[(size_t)kk * 25 + jj];
                else if (jj < 37) v = cWs[(size_t)kk * 12 + (jj - 25)];
                else              v = cWm[(size_t)kk * 25 + (jj - 37)];
            }
            WhcT[(size_t)n * 320 + k] = f2b(v);
        }
    }
}

// ---------------------------------------------------------------------------
// gemm_encp: encoder GEMM, register-staged A directly from se/pz f32
// (no Acat materialization). part[z] = (se|pz) @ WcatT^T slice, f32 partials.
// grid (2, 32, 6), K=5769, kchunk=992. ldc=228, slice stride 4096*228.
// ---------------------------------------------------------------------------
__global__ __launch_bounds__(256) void gemm_encp(
    const float* __restrict__ se, const float* __restrict__ pz,
    const unsigned short* __restrict__ WT,
    float* __restrict__ part) {
    __shared__ unsigned short As[128 * 40];
    __shared__ unsigned short Bs[128 * 40];
    const int tid = threadIdx.x;
    const int m0 = blockIdx.y * 128, n0 = blockIdx.x * 128;
    const int kbeg = blockIdx.z * 992;
    const int kend = min(kbeg + 992, 5769);
    const int lane = tid & 63, w = tid >> 6;
    const int wm = w >> 1, wn = w & 1;
    const int quad = lane >> 4, l16 = lane & 15;

    f4 acc[4][4] = {};
    ushort4 pa[4], pb[4];

    auto loadA = [&](int k0) {
#pragma unroll
        for (int i = 0; i < 4; i++) {
            int f = tid + i * 256;
            int r = f >> 3, cc = (f & 7) * 4;
            int gm = m0 + r;
            float tv[4];
#pragma unroll
            for (int j = 0; j < 4; j++) {
                int k = k0 + cc + j;
                float v = 0.f;
                if (k < kend) {
                    v = (k < 5705) ? se[(size_t)gm * 5705 + k]
                                   : pz[(size_t)gm * 64 + (k - 5705)];
                }
                tv[j] = v;
            }
            ushort4 val;
            val.x = f2b(tv[0]); val.y = f2b(tv[1]); val.z = f2b(tv[2]); val.w = f2b(tv[3]);
            pa[i] = val;
        }
    };
    auto loadB = [&](int k0) {
        const bool full = (kend - k0) >= 32;
#pragma unroll
        for (int i = 0; i < 4; i++) {
            int f = tid + i * 256;
            int r = f >> 3, cc = (f & 7) * 4;
            int gn = n0 + r;
            ushort4 val;
            if (gn < 227) {
                if (full) {
                    val = *(const ushort4*)(WT + (size_t)gn * 5792 + k0 + cc);
                } else {
                    unsigned short tv[4];
#pragma unroll
                    for (int j = 0; j < 4; j++) {
                        int k = k0 + cc + j;
                        tv[j] = (k < kend) ? WT[(size_t)gn * 5792 + k] : (unsigned short)0;
                    }
                    val.x = tv[0]; val.y = tv[1]; val.z = tv[2]; val.w = tv[3];
                }
            } else {
                val.x = val.y = val.z = val.w = 0;
            }
            pb[i] = val;
        }
    };

    loadA(kbeg); loadB(kbeg);
    for (int k0 = kbeg; k0 < kend; k0 += 32) {
#pragma unroll
        for (int i = 0; i < 4; i++) {
            int f = tid + i * 256;
            int r = f >> 3, cc = (f & 7) * 4;
            *(ushort4*)&As[r * 40 + cc] = pa[i];
        }
#pragma unroll
        for (int i = 0; i < 4; i++) {
            int f = tid + i * 256;
            int r = f >> 3, cc = (f & 7) * 4;
            *(ushort4*)&Bs[r * 40 + cc] = pb[i];
        }
        __syncthreads();
        if (k0 + 32 < kend) { loadA(k0 + 32); loadB(k0 + 32); }
        s8 a[4], b[4];
#pragma unroll
        for (int mi = 0; mi < 4; mi++)
            a[mi] = *(const s8*)&As[(wm * 64 + mi * 16 + l16) * 40 + quad * 8];
#pragma unroll
        for (int ni = 0; ni < 4; ni++)
            b[ni] = *(const s8*)&Bs[(wn * 64 + ni * 16 + l16) * 40 + quad * 8];
#pragma unroll
        for (int mi = 0; mi < 4; mi++)
#pragma unroll
            for (int ni = 0; ni < 4; ni++)
                acc[mi][ni] = __builtin_amdgcn_mfma_f32_16x16x32_bf16(
                    a[mi], b[ni], acc[mi][ni], 0, 0, 0);
        __syncthreads();
    }

    float* C = part + (size_t)blockIdx.z * 4096 * 228;
#pragma unroll
    for (int mi = 0; mi < 4; mi++) {
        int gmb = m0 + wm * 64 + mi * 16 + quad * 4;
#pragma unroll
        for (int ni = 0; ni < 4; ni++) {
            int gn = n0 + wn * 64 + ni * 16 + l16;
            if (gn < 227) {
#pragma unroll
                for (int r = 0; r < 4; r++)
                    C[(size_t)(gmb + r) * 228 + gn] = acc[mi][ni][r];
            }
        }
    }
}

// ---------------------------------------------------------------------------
// red_enc4: finb = bf16(sum_{z<6} part_enc), float4 loads. grid (1,1024).
// ---------------------------------------------------------------------------
__global__ __launch_bounds__(256) void red_enc4(const float* __restrict__ part,
                                                unsigned short* __restrict__ finb) {
    const int t = threadIdx.x;
    const int row = blockIdx.y * 4 + (t >> 6);
    const int cw = t & 63;
    if (cw < 57) {
        const float* p = part + (size_t)row * 228 + cw * 4;
        float4 s = make_float4(0.f, 0.f, 0.f, 0.f);
#pragma unroll
        for (int z = 0; z < 6; z++) {
            float4 v = *(const float4*)(p + (size_t)z * 4096 * 228);
            s.x += v.x; s.y += v.y; s.z += v.z; s.w += v.w;
        }
        if (cw == 56) s.w = 0.f;
        ushort4 o;
        o.x = f2b(s.x); o.y = f2b(s.y); o.z = f2b(s.z); o.w = f2b(s.w);
        *(ushort4*)(finb + (size_t)row * 256 + cw * 4) = o;
    } else {
        ushort4 z4 = make_ushort4(0, 0, 0, 0);
        *(ushort4*)(finb + (size_t)row * 256 + 228 + (cw - 57) * 4) = z4;
    }
}

// ---------------------------------------------------------------------------
// red_cf3_k: fused c3 + f3 partial reduction. grid (1280), block 256.
// ---------------------------------------------------------------------------
__global__ __launch_bounds__(256) void red_cf3_k(
    const float* __restrict__ part_c3, const float* __restrict__ cb3,
    float* __restrict__ ctxb,
    const float* __restrict__ part_f3, const float* __restrict__ fb3,
    float* __restrict__ flat) {
    const int bx = blockIdx.x, t = threadIdx.x;
    if (bx < 256) {
        int idx = bx * 256 + t;
        int row = idx >> 4, c4 = idx & 15;
        float4 s = *(const float4*)(cb3 + c4 * 4);
        const float* p = part_c3 + (size_t)row * 64 + c4 * 4;
#pragma unroll
        for (int z = 0; z < 8; z++) {
            float4 v = *(const float4*)(p + (size_t)z * 4096 * 64);
            s.x += v.x; s.y += v.y; s.z += v.z; s.w += v.w;
        }
        *(float4*)(ctxb + (size_t)row * 64 + c4 * 4) = s;
    } else {
        const int by = bx - 256;
        const int row = by * 4 + (t >> 6);
        const int cw = t & 63;
        if (cw >= 57) return;
        float b[4];
#pragma unroll
        for (int j = 0; j < 4; j++) {
            int col = cw * 4 + j;
            b[j] = (col < 227) ? fb3[col] : 0.f;
        }
        const float* p = part_f3 + (size_t)row * 228 + cw * 4;
        float4 s = make_float4(b[0], b[1], b[2], b[3]);
#pragma unroll
        for (int z = 0; z < 4; z++) {
            float4 v = *(const float4*)(p + (size_t)z * 4096 * 228);
            s.x += v.x; s.y += v.y; s.z += v.z; s.w += v.w;
        }
        if (cw == 56) s.w = 0.f;
        *(float4*)(flat + (size_t)row * 228 + cw * 4) = s;
    }
}

// ---------------------------------------------------------------------------
// gemm_dualg: dual-problem GEMM, per-z (A,lda,K,W,ldw,bias,C). N=1024, ldc=1024,
// out bf16(softplus(.+bias)). grid (8,32,2).
// ---------------------------------------------------------------------------
__global__ __launch_bounds__(256) void gemm_dualg(
    const unsigned short* __restrict__ A0, int lda0, int K0,
    const unsigned short* __restrict__ A1, int lda1, int K1,
    const unsigned short* __restrict__ W0, int ldw0,
    const unsigned short* __restrict__ W1, int ldw1,
    const float* __restrict__ b0, const float* __restrict__ b1,
    unsigned short* __restrict__ C0, unsigned short* __restrict__ C1) {
    __shared__ __align__(16) unsigned short As[128 * 32];
    __shared__ __align__(16) unsigned short Bs[128 * 32];
    const int z = blockIdx.z;
    const unsigned short* __restrict__ A  = z ? A1 : A0;
    const unsigned short* __restrict__ WT = z ? W1 : W0;
    const float* __restrict__ bias        = z ? b1 : b0;
    unsigned short* __restrict__ C        = z ? C1 : C0;
    const int lda = z ? lda1 : lda0;
    const int ldw = z ? ldw1 : ldw0;
    const int K   = z ? K1 : K0;
    const int tid = threadIdx.x;
    const int m0 = blockIdx.y * 128, n0 = blockIdx.x * 128;
    const int lane = tid & 63, w = tid >> 6;
    const int wm = w >> 1, wn = w & 1;
    const int quad = lane >> 4, l16 = lane & 15;
    const int dr = lane >> 2;
    const int dk = (lane & 3) * 8;

    f4 acc[4][4] = {};

    for (int k0 = 0; k0 < K; k0 += 32) {
#pragma unroll
        for (int c = 0; c < 2; c++) {
            int rr = w * 32 + c * 16;
            glds16(A + (size_t)(m0 + rr + dr) * lda + k0 + dk, &As[rr * 32]);
            glds16(WT + (size_t)(n0 + rr + dr) * ldw + k0 + dk, &Bs[rr * 32]);
        }
        __syncthreads();
        s8 a[4], b[4];
#pragma unroll
        for (int mi = 0; mi < 4; mi++)
            a[mi] = *(const s8*)&As[(wm * 64 + mi * 16 + l16) * 32 + quad * 8];
#pragma unroll
        for (int ni = 0; ni < 4; ni++)
            b[ni] = *(const s8*)&Bs[(wn * 64 + ni * 16 + l16) * 32 + quad * 8];
#pragma unroll
        for (int mi = 0; mi < 4; mi++)
#pragma unroll
            for (int ni = 0; ni < 4; ni++)
                acc[mi][ni] = __builtin_amdgcn_mfma_f32_16x16x32_bf16(
                    a[mi], b[ni], acc[mi][ni], 0, 0, 0);
        __syncthreads();
    }

#pragma unroll
    for (int mi = 0; mi < 4; mi++) {
        int gmb = m0 + wm * 64 + mi * 16 + quad * 4;
#pragma unroll
        for (int ni = 0; ni < 4; ni++) {
            int gn = n0 + wn * 64 + ni * 16 + l16;
#pragma unroll
            for (int r = 0; r < 4; r++) {
                float v = acc[mi][ni][r] + bias[gn];
                C[(size_t)(gmb + r) * 1024 + gn] = f2b(softplus_f(v));
            }
        }
    }
}

// ---------------------------------------------------------------------------
// part_cf3_k: fused c3 (z<8) + f3 (z>=8) split-K partial GEMMs. grid (2,32,12).
// ---------------------------------------------------------------------------
__global__ __launch_bounds__(256) void part_cf3_k(
    const unsigned short* __restrict__ h2c, const unsigned short* __restrict__ cW3T,
    const unsigned short* __restrict__ h2f, const unsigned short* __restrict__ fW3T,
    float* __restrict__ part_c3, float* __restrict__ part_f3) {
    __shared__ __align__(16) unsigned short As[128 * 32];
    __shared__ __align__(16) unsigned short Bs[128 * 32];
    const int z = blockIdx.z;
    const bool isC = (z < 8);
    if (isC && blockIdx.x != 0) return;
    const unsigned short* __restrict__ A  = isC ? h2c : h2f;
    const unsigned short* __restrict__ WT = isC ? cW3T : fW3T;
    const int N   = isC ? 64 : 227;
    const int ldc = isC ? 64 : 228;
    const int zz  = isC ? z : z - 8;
    const int kbeg = zz * (isC ? 128 : 256);
    const int kend = kbeg + (isC ? 128 : 256);
    float* __restrict__ C = (isC ? part_c3 : part_f3) + (size_t)zz * 4096 * ldc;
    const int tid = threadIdx.x;
    const int m0 = blockIdx.y * 128, n0 = blockIdx.x * 128;
    const int lane = tid & 63, w = tid >> 6;
    const int wm = w >> 1, wn = w & 1;
    const int quad = lane >> 4, l16 = lane & 15;
    const int dr = lane >> 2;
    const int dk = (lane & 3) * 8;

    f4 acc[4][4] = {};

    for (int k0 = kbeg; k0 < kend; k0 += 32) {
#pragma unroll
        for (int c = 0; c < 2; c++) {
            int rr = w * 32 + c * 16;
            glds16(A + (size_t)(m0 + rr + dr) * 1024 + k0 + dk, &As[rr * 32]);
            glds16(WT + (size_t)(n0 + rr + dr) * 1024 + k0 + dk, &Bs[rr * 32]);
        }
        __syncthreads();
        s8 a[4], b[4];
#pragma unroll
        for (int mi = 0; mi < 4; mi++)
            a[mi] = *(const s8*)&As[(wm * 64 + mi * 16 + l16) * 32 + quad * 8];
#pragma unroll
        for (int ni = 0; ni < 4; ni++)
            b[ni] = *(const s8*)&Bs[(wn * 64 + ni * 16 + l16) * 32 + quad * 8];
#pragma unroll
        for (int mi = 0; mi < 4; mi++)
#pragma unroll
            for (int ni = 0; ni < 4; ni++)
                acc[mi][ni] = __builtin_amdgcn_mfma_f32_16x16x32_bf16(
                    a[mi], b[ni], acc[mi][ni], 0, 0, 0);
        __syncthreads();
    }

#pragma unroll
    for (int mi = 0; mi < 4; mi++) {
        int gmb = m0 + wm * 64 + mi * 16 + quad * 4;
#pragma unroll
        for (int ni = 0; ni < 4; ni++) {
            int gn = n0 + wn * 64 + ni * 16 + l16;
            if (gn < N) {
#pragma unroll
                for (int r = 0; r < 4; r++)
                    C[(size_t)(gmb + r) * ldc + gn] = acc[mi][ni][r];
            }
        }
    }
}

// ---------------------------------------------------------------------------
// tail_k: g-net (blocks 0..1815, 2 elems/thread — r8 config) || Ah concat
// (blocks 1816..5911). block 256.
// ---------------------------------------------------------------------------
__global__ __launch_bounds__(256) void tail_k(
    const float* __restrict__ flat,
    const float* __restrict__ gW1, const float* __restrict__ b1s,
    const float* __restrict__ w2s, const float* __restrict__ gb2,
    const float* __restrict__ ctxb, unsigned short* __restrict__ Ah,
    float* __restrict__ out) {
    __shared__ float4 wt[228];
    const int bid = blockIdx.x, t = threadIdx.x;
    if (bid < 1816) {
        const int d = bid >> 3;          // 0..226
        const int y = bid & 7;
        if (t < 227) {
            size_t o = (size_t)d * 227 + t;
            wt[t] = make_float4(gW1[o], b1s[o], w2s[o], 0.f);
        } else if (t == 227) {
            wt[227] = make_float4(0.f, 0.f, 0.f, 0.f);
        }
        __syncthreads();
        const int b0 = y * 512 + t;
        float x0 = flat[(size_t)b0 * 228 + d] * 1.44269504f;
        float x1 = flat[(size_t)(b0 + 256) * 228 + d] * 1.44269504f;
        const float g2 = gb2[d];
        float a0 = g2, a1 = g2;
        float4 w = wt[0];
#pragma unroll 2
        for (int h = 0; h < 227; h++) {
            float4 wn = wt[h + 1];
            float z0 = fmaf(x0, w.x, w.y);
            float z1 = fmaf(x1, w.x, w.y);
            a0 = fmaf(log2_f(1.f + exp2_f(z0)), w.z, a0);
            a1 = fmaf(log2_f(1.f + exp2_f(z1)), w.z, a1);
            w = wn;
        }
        out[(size_t)b0 * 415 + 62 + d] = sigmoid_f(a0);
        out[(size_t)(b0 + 256) * 415 + 62 + d] = sigmoid_f(a1);
    } else {
        const int row = bid - 1816;
        float v = 0.f;
        if (t < 227) v = flat[(size_t)row * 228 + t];
        Ah[(size_t)row * 320 + t] = f2b(v);
        if (t < 64) Ah[(size_t)row * 320 + 256 + t] = f2b(ctxb[(size_t)row * 64 + t]);
    }
}

// ---------------------------------------------------------------------------
// gemm_heads_k: heads GEMM (M=4096, N=126, K=320) with fused final epilogue.
// grid (32), block 256.
// ---------------------------------------------------------------------------
__global__ __launch_bounds__(256) void gemm_heads_k(
    const unsigned short* __restrict__ Ah, const unsigned short* __restrict__ WhcT,
    const float* __restrict__ ctxb, float* __restrict__ out) {
    __shared__ __align__(16) unsigned short As[128 * 32];
    __shared__ __align__(16) unsigned short Bs[128 * 32];
    __shared__ float cT[64][129];
    const int tid = threadIdx.x;
    const int m0 = blockIdx.x * 128;
    const int lane = tid & 63, w = tid >> 6;
    const int wm = w >> 1, wn = w & 1;
    const int quad = lane >> 4, l16 = lane & 15;
    const int dr = lane >> 2;
    const int dk = (lane & 3) * 8;

    f4 acc[4][4] = {};

    for (int k0 = 0; k0 < 320; k0 += 32) {
#pragma unroll
        for (int c = 0; c < 2; c++) {
            int rr = w * 32 + c * 16;
            glds16(Ah + (size_t)(m0 + rr + dr) * 320 + k0 + dk, &As[rr * 32]);
            glds16(WhcT + (size_t)(rr + dr) * 320 + k0 + dk, &Bs[rr * 32]);
        }
        __syncthreads();
        s8 a[4], b[4];
#pragma unroll
        for (int mi = 0; mi < 4; mi++)
            a[mi] = *(const s8*)&As[(wm * 64 + mi * 16 + l16) * 32 + quad * 8];
#pragma unroll
        for (int ni = 0; ni < 4; ni++)
            b[ni] = *(const s8*)&Bs[(wn * 64 + ni * 16 + l16) * 32 + quad * 8];
#pragma unroll
        for (int mi = 0; mi < 4; mi++)
#pragma unroll
            for (int ni = 0; ni < 4; ni++)
                acc[mi][ni] = __builtin_amdgcn_mfma_f32_16x16x32_bf16(
                    a[mi], b[ni], acc[mi][ni], 0, 0, 0);
        __syncthreads();
    }

#pragma unroll
    for (int pass = 0; pass < 2; pass++) {
        if (wm == pass) {
#pragma unroll
            for (int mi = 0; mi < 4; mi++) {
                int rl = mi * 16 + quad * 4;
#pragma unroll
                for (int ni = 0; ni < 4; ni++) {
                    int cl = wn * 64 + ni * 16 + l16;
#pragma unroll
                    for (int r = 0; r < 4; r++)
                        cT[rl + r][cl] = acc[mi][ni][r];
                }
            }
        }
        __syncthreads();
        if (tid < 64) {
            const int bidx = m0 + pass * 64 + tid;
            float* ob = out + (size_t)bidx * 415;
            const float* row = cT[tid];
            float sraw[12], craw[12];
#pragma unroll
            for (int j = 0; j < 25; j++) ob[j] = row[j];
#pragma unroll
            for (int j = 0; j < 12; j++) sraw[j] = row[25 + j];
#pragma unroll
            for (int j = 0; j < 25; j++) ob[37 + j] = row[37 + j];
#pragma unroll
            for (int j = 0; j < 25; j++) ob[289 + j] = row[64 + j];
#pragma unroll
            for (int j = 0; j < 12; j++) craw[j] = row[89 + j];
#pragma unroll
            for (int j = 0; j < 25; j++) ob[326 + j] = row[101 + j];
            const float lsf = lse12(sraw), lsc = lse12(craw);
#pragma unroll
            for (int j = 0; j < 12; j++) {
                ob[25 + j] = sraw[j] - lsf;
                ob[314 + j] = craw[j] - lsc;
            }
            for (int k = 0; k < 64; k++)
                ob[351 + k] = ctxb[(size_t)bidx * 64 + k];
        }
        __syncthreads();
    }
}

// ---------------------------------------------------------------------------
// ---------------- FALLBACK path kernels (r6 known-good) --------------------
// ---------------------------------------------------------------------------
__global__ __launch_bounds__(256) void transpose_w(const float* __restrict__ src,
                                                   unsigned short* __restrict__ dst,
                                                   int K, int N, int Kpad, int Npad) {
    __shared__ float tile[32][33];
    const int n0 = blockIdx.x * 32, k0 = blockIdx.y * 32;
    const int tx = threadIdx.x, ty = threadIdx.y;
#pragma unroll
    for (int r = 0; r < 4; r++) {
        int k = k0 + ty + r * 8, n = n0 + tx;
        tile[ty + r * 8][tx] = (k < K && n < N) ? src[(size_t)k * N + n] : 0.f;
    }
    __syncthreads();
#pragma unroll
    for (int r = 0; r < 4; r++) {
        int n = n0 + ty + r * 8, k = k0 + tx;
        if (n < Npad && k < Kpad) dst[(size_t)n * Kpad + k] = f2b(tile[tx][ty + r * 8]);
    }
}

__global__ __launch_bounds__(256) void wcat_t(const float* __restrict__ Wref,
                                              unsigned short* __restrict__ dst) {
    __shared__ float tile[32][33];
    const int n0 = blockIdx.x * 32, k0 = blockIdx.y * 32;
    const int tx = threadIdx.x, ty = threadIdx.y;
#pragma unroll
    for (int r = 0; r < 4; r++) {
        int k = k0 + ty + r * 8, n = n0 + tx;
        float v = 0.f;
        if (n < 227 && k < 5769) {
            if (k < 5705) {
                int wrow = k + 64 * (k / 163);
                v = Wref[(size_t)wrow * 227 + n];
            } else {
                int j2 = k - 5705;
                for (int t = 0; t < 35; t++)
                    v += Wref[(size_t)(t * 227 + 163 + j2) * 227 + n];
            }
        }
        tile[ty + r * 8][tx] = v;
    }
    __syncthreads();
#pragma unroll
    for (int r = 0; r < 4; r++) {
        int n = n0 + ty + r * 8, k = k0 + tx;
        if (n < 256 && k < 5792) dst[(size_t)n * 5792 + k] = f2b(tile[tx][ty + r * 8]);
    }
}

__global__ __launch_bounds__(256) void gscale_k(const float* __restrict__ gb1,
                                                const float* __restrict__ gW2,
                                                float* __restrict__ b1s,
                                                float* __restrict__ w2s) {
    int i = blockIdx.x * 256 + threadIdx.x;
    if (i < 227 * 227) {
        b1s[i] = gb1[i] * 1.44269504f;
        w2s[i] = gW2[i] * 0.69314718f;
    }
}

__global__ __launch_bounds__(256) void fillb_k(float* __restrict__ buf,
                                               const float* __restrict__ bias,
                                               int ld, int ncr) {
    const int row = blockIdx.y;
    const int col = blockIdx.x * 256 + threadIdx.x;
    if (col >= ld) return;
    float v = 0.f;
    if (bias && col < ncr) v = bias[col];
    buf[(size_t)row * ld + col] = v;
}

template <int AMODE, int ACT, bool ATOMIC, bool OBF16>
__global__ __launch_bounds__(256) void gemm_mfma(
    const void* __restrict__ Aptr, int lda,
    const float* __restrict__ A2ptr,
    const unsigned short* __restrict__ WT, int ldwt,
    const float* __restrict__ bias,
    void* __restrict__ Cptr, int ldc,
    int M, int N, int K, int kchunk) {
    __shared__ unsigned short As[128 * 40];
    __shared__ unsigned short Bs[128 * 40];
    const int tid = threadIdx.x;
    const int m0 = blockIdx.y * 128, n0 = blockIdx.x * 128;
    const int kbeg = blockIdx.z * kchunk;
    const int kend = min(kbeg + kchunk, K);
    const int lane = tid & 63, w = tid >> 6;
    const int wm = w >> 1, wn = w & 1;
    const int quad = lane >> 4, l16 = lane & 15;

    f4 acc[4][4] = {};
    ushort4 pa[4], pb[4];

    auto loadA = [&](int k0) {
        const bool full = (kend - k0) >= 32;
#pragma unroll
        for (int i = 0; i < 4; i++) {
            int f = tid + i * 256;
            int r = f >> 3, cc = (f & 7) * 4;
            int gm = m0 + r;
            ushort4 val;
            if (AMODE == 0) {
                const float* A = (const float*)Aptr;
                float t[4];
#pragma unroll
                for (int j = 0; j < 4; j++) {
                    int k = k0 + cc + j;
                    t[j] = (k < kend) ? A[(size_t)gm * lda + k] : 0.f;
                }
                val.x = f2b(t[0]); val.y = f2b(t[1]); val.z = f2b(t[2]); val.w = f2b(t[3]);
            } else if (AMODE == 1) {
                const unsigned short* A = (const unsigned short*)Aptr;
                if (full) {
                    val = *(const ushort4*)(A + (size_t)gm * lda + k0 + cc);
                } else {
                    unsigned short t[4];
#pragma unroll
                    for (int j = 0; j < 4; j++) {
                        int k = k0 + cc + j;
                        t[j] = (k < kend) ? A[(size_t)gm * lda + k] : (unsigned short)0;
                    }
                    val.x = t[0]; val.y = t[1]; val.z = t[2]; val.w = t[3];
                }
            } else {
                const float* se = (const float*)Aptr;
                float t[4];
#pragma unroll
                for (int j = 0; j < 4; j++) {
                    int k = k0 + cc + j;
                    float v = 0.f;
                    if (k < kend) {
                        v = (k < 5705) ? se[(size_t)gm * 5705 + k]
                                       : A2ptr[(size_t)gm * 64 + (k - 5705)];
                    }
                    t[j] = v;
                }
                val.x = f2b(t[0]); val.y = f2b(t[1]); val.z = f2b(t[2]); val.w = f2b(t[3]);
            }
            pa[i] = val;
        }
    };
    auto loadB = [&](int k0) {
        const bool full = (kend - k0) >= 32;
#pragma unroll
        for (int i = 0; i < 4; i++) {
            int f = tid + i * 256;
            int r = f >> 3, cc = (f & 7) * 4;
            int gn = n0 + r;
            ushort4 val;
            if (gn < N) {
                if (full) {
                    val = *(const ushort4*)(WT + (size_t)gn * ldwt + k0 + cc);
                } else {
                    unsigned short t[4];
#pragma unroll
                    for (int j = 0; j < 4; j++) {
                        int k = k0 + cc + j;
                        t[j] = (k < kend) ? WT[(size_t)gn * ldwt + k] : (unsigned short)0;
                    }
                    val.x = t[0]; val.y = t[1]; val.z = t[2]; val.w = t[3];
                }
            } else {
                val.x = val.y = val.z = val.w = 0;
            }
            pb[i] = val;
        }
    };

    loadA(kbeg); loadB(kbeg);
    for (int k0 = kbeg; k0 < kend; k0 += 32) {
#pragma unroll
        for (int i = 0; i < 4; i++) {
            int f = tid + i * 256;
            int r = f >> 3, cc = (f & 7) * 4;
            *(ushort4*)&As[r * 40 + cc] = pa[i];
        }
#pragma unroll
        for (int i = 0; i < 4; i++) {
            int f = tid + i * 256;
            int r = f >> 3, cc = (f & 7) * 4;
            *(ushort4*)&Bs[r * 40 + cc] = pb[i];
        }
        __syncthreads();
        if (k0 + 32 < kend) { loadA(k0 + 32); loadB(k0 + 32); }
        s8 a[4], b[4];
#pragma unroll
        for (int mi = 0; mi < 4; mi++)
            a[mi] = *(const s8*)&As[(wm * 64 + mi * 16 + l16) * 40 + quad * 8];
#pragma unroll
        for (int ni = 0; ni < 4; ni++)
            b[ni] = *(const s8*)&Bs[(wn * 64 + ni * 16 + l16) * 40 + quad * 8];
#pragma unroll
        for (int mi = 0; mi < 4; mi++)
#pragma unroll
            for (int ni = 0; ni < 4; ni++)
                acc[mi][ni] = __builtin_amdgcn_mfma_f32_16x16x32_bf16(
                    a[mi], b[ni], acc[mi][ni], 0, 0, 0);
        __syncthreads();
    }
#pragma unroll
    for (int mi = 0; mi < 4; mi++) {
        int gmb = m0 + wm * 64 + mi * 16 + quad * 4;
#pragma unroll
        for (int ni = 0; ni < 4; ni++) {
            int gn = n0 + wn * 64 + ni * 16 + l16;
            if (gn < N) {
#pragma unroll
                for (int r = 0; r < 4; r++) {
                    float v = acc[mi][ni][r];
                    size_t off = (size_t)(gmb + r) * ldc + gn;
                    if (ATOMIC) {
                        atomicAdd((float*)Cptr + off, v);
                    } else {
                        if (bias) v += bias[gn];
                        if (ACT == 1) v = softplus_f(v);
                        if (OBF16) ((unsigned short*)Cptr)[off] = f2b(v);
                        else ((float*)Cptr)[off] = v;
                    }
                }
            }
        }
    }
}

__global__ __launch_bounds__(256) void g_kernel2(
    const float* __restrict__ flat,
    const float* __restrict__ gW1, const float* __restrict__ b1s,
    const float* __restrict__ w2s, const float* __restrict__ gb2,
    float* __restrict__ out) {
    __shared__ float4 wt[228];
    const int d = blockIdx.x;
    const int t = threadIdx.x;
    if (t < 227) {
        size_t o = (size_t)d * 227 + t;
        wt[t] = make_float4(gW1[o], b1s[o], w2s[o], 0.f);
    } else if (t == 227) {
        wt[227] = make_float4(0.f, 0.f, 0.f, 0.f);
    }
    __syncthreads();
    const int b0 = blockIdx.y * 512 + t;
    float x0 = flat[(size_t)b0 * 228 + d] * 1.44269504f;
    float x1 = flat[(size_t)(b0 + 256) * 228 + d] * 1.44269504f;
    const float g2 = gb2[d];
    float a0 = g2, a1 = g2;
    float4 w = wt[0];
#pragma unroll 2
    for (int h = 0; h < 227; h++) {
        float4 wn = wt[h + 1];
        float z0 = fmaf(x0, w.x, w.y);
        float z1 = fmaf(x1, w.x, w.y);
        a0 = fmaf(log2_f(1.f + exp2_f(z0)), w.z, a0);
        a1 = fmaf(log2_f(1.f + exp2_f(z1)), w.z, a1);
        w = wn;
    }
    out[(size_t)b0 * 415 + 62 + d] = sigmoid_f(a0);
    out[(size_t)(b0 + 256) * 415 + 62 + d] = sigmoid_f(a1);
}

__global__ __launch_bounds__(256) void heads_k(
    const float* __restrict__ flat, const float* __restrict__ ctx,
    const float* __restrict__ Wl, const float* __restrict__ Wsh, const float* __restrict__ Wm,
    const float* __restrict__ cWl, const float* __restrict__ cWsh, const float* __restrict__ cWm,
    float* __restrict__ out) {
    __shared__ float fl[227];
    __shared__ float cx[64];
    __shared__ float sraw[12], craw[12];
    __shared__ float lsf, lsc;
    const int b = blockIdx.x;
    const int t = threadIdx.x;
    if (t < 227) fl[t] = flat[(size_t)b * 228 + t];
    if (t < 64) cx[t] = ctx[(size_t)b * 64 + t];
    __syncthreads();
    float* ob = out + (size_t)b * 415;

    if (t < 25) {
        float a = 0.f;
        for (int k = 0; k < 227; k++) a = fmaf(fl[k], Wl[(size_t)k * 25 + t], a);
        ob[t] = a;
    } else if (t < 37) {
        int j = t - 25;
        float a = 0.f;
        for (int k = 0; k < 227; k++) a = fmaf(fl[k], Wsh[(size_t)k * 12 + j], a);
        sraw[j] = a;
    } else if (t < 62) {
        int j = t - 37;
        float a = 0.f;
        for (int k = 0; k < 227; k++) a = fmaf(fl[k], Wm[(size_t)k * 25 + j], a);
        ob[37 + j] = a;
    } else if (t >= 64 && t < 126) {
        int j2 = t - 64;
        if (j2 < 25) {
            float a = 0.f;
            for (int k = 0; k < 64; k++) a = fmaf(cx[k], cWl[(size_t)k * 25 + j2], a);
            ob[289 + j2] = a;
        } else if (j2 < 37) {
            int j = j2 - 25;
            float a = 0.f;
            for (int k = 0; k < 64; k++) a = fmaf(cx[k], cWsh[(size_t)k * 12 + j], a);
            craw[j] = a;
        } else {
            int j = j2 - 37;
            float a = 0.f;
            for (int k = 0; k < 64; k++) a = fmaf(cx[k], cWm[(size_t)k * 25 + j], a);
            ob[326 + j] = a;
        }
    } else if (t >= 128 && t < 192) {
        ob[351 + (t - 128)] = cx[t - 128];
    }
    __syncthreads();
    if (t == 0) lsf = lse12(sraw);
    if (t == 64) lsc = lse12(craw);
    __syncthreads();
    if (t < 12) ob[25 + t] = sraw[t] - lsf;
    else if (t >= 64 && t < 76) ob[314 + (t - 64)] = craw[t - 64] - lsc;
}

// ---------------------------------------------------------------------------
extern "C" void kernel_launch(void* const* d_in, const int* in_sizes, int n_in,
                              void* d_out, int out_size, void* d_ws, size_t ws_size,
                              hipStream_t stream) {
    const float* se    = (const float*)d_in[0];
    const float* pz    = (const float*)d_in[1];
    const float* Wref  = (const float*)d_in[2];
    const float* fW1   = (const float*)d_in[3];
    const float* fb1   = (const float*)d_in[4];
    const float* fW2   = (const float*)d_in[5];
    const float* fb2   = (const float*)d_in[6];
    const float* fW3   = (const float*)d_in[7];
    const float* fb3   = (const float*)d_in[8];
    const float* gW1   = (const float*)d_in[9];
    const float* gb1   = (const float*)d_in[10];
    const float* gW2   = (const float*)d_in[11];
    const float* gb2   = (const float*)d_in[12];
    const float* Wland = (const float*)d_in[13];
    const float* Wshot = (const float*)d_in[14];
    const float* Wmove = (const float*)d_in[15];
    const float* cW1   = (const float*)d_in[16];
    const float* cb1   = (const float*)d_in[17];
    const float* cW2   = (const float*)d_in[18];
    const float* cb2   = (const float*)d_in[19];
    const float* cW3   = (const float*)d_in[20];
    const float* cb3   = (const float*)d_in[21];
    const float* cWl   = (const float*)d_in[22];
    const float* cWs   = (const float*)d_in[23];
    const float* cWm   = (const float*)d_in[24];
    float* out = (float*)d_out;
    const int M = 4096;

    char* p = (char*)d_ws;
    auto alloc = [&](size_t bytes) {
        char* r = p;
        p += (bytes + 255) & ~(size_t)255;
        return r;
    };
    // ---- common base ----
    unsigned short* WcatT = (unsigned short*)alloc((size_t)256 * 5792 * 2);
    unsigned short* cW1T  = (unsigned short*)alloc((size_t)1024 * 64 * 2);
    unsigned short* cW2T  = (unsigned short*)alloc((size_t)1024 * 1024 * 2);
    unsigned short* cW3T  = (unsigned short*)alloc((size_t)128 * 1024 * 2);
    unsigned short* fW1T  = (unsigned short*)alloc((size_t)1024 * 256 * 2);
    unsigned short* fW2T  = (unsigned short*)alloc((size_t)1024 * 1024 * 2);
    unsigned short* fW3T  = (unsigned short*)alloc((size_t)256 * 1024 * 2);
    float* fin  = (float*)alloc((size_t)M * 228 * 4);   // fallback target; full: partial span base
    float* flat = (float*)alloc((size_t)M * 228 * 4);
    float* ctxb = (float*)alloc((size_t)M * 64 * 4);
    unsigned short* h2b  = (unsigned short*)alloc((size_t)M * 1024 * 2);  // c-chain h2
    unsigned short* h1fb = (unsigned short*)alloc((size_t)M * 1024 * 2);  // c-chain h1
    float* b1s = (float*)alloc((size_t)227 * 227 * 4);
    float* w2s = (float*)alloc((size_t)227 * 227 * 4);

    size_t base_used = (size_t)(p - (char*)d_ws);
    size_t full_extra = (size_t)M * 64 * 2            // pzb
                      + (size_t)M * 256 * 2           // finb
                      + (size_t)M * 5792 * 2          // region
                      + (size_t)128 * 320 * 2 + 1024; // WhcT
    const bool full = (base_used + full_extra + 65536) <= ws_size;

    if (full) {
        unsigned short* pzb  = (unsigned short*)alloc((size_t)M * 64 * 2);
        unsigned short* finb = (unsigned short*)alloc((size_t)M * 256 * 2);
        char* region = alloc((size_t)M * 5792 * 2);                     // 45.25 MiB
        unsigned short* WhcT = (unsigned short*)alloc((size_t)128 * 320 * 2);
        float* part_enc = fin;  // spans fin..h1fb (24.1 MiB >= 6*3.56 MiB)
        unsigned short* h2fb   = (unsigned short*)region;                            // [0, 8 MiB)
        float* part_c3         = (float*)(region + (size_t)8 * 1024 * 1024);         // 8 MiB
        unsigned short* h1f    = (unsigned short*)(region + (size_t)16 * 1024 * 1024);
        float* part_f3         = (float*)(region + (size_t)24 * 1024 * 1024);        // 14.25 MiB
        unsigned short* Ah     = (unsigned short*)(region + (size_t)41 * 1024 * 1024);
        unsigned short* h1c = h1fb;
        unsigned short* h2c = h2b;

        // 1. prep (weights + misc only; NO Acat)
        prep_all_k<<<dim3(5586), 256, 0, stream>>>(
            cW1, cW2, cW3, fW1, fW2, fW3, cW1T, cW2T, cW3T, fW1T, fW2T, fW3T,
            Wref, WcatT, pz, pzb, gb1, gW2, b1s, w2s,
            Wland, Wshot, Wmove, cWl, cWs, cWm, WhcT);

        // 2. encoder: register-staged from se/pz f32 directly, partial z=6
        gemm_encp<<<dim3(2, 32, 6), 256, 0, stream>>>(se, pz, WcatT, part_enc);
        // 3. reduce -> finb bf16
        red_enc4<<<dim3(1, 1024), 256, 0, stream>>>(part_enc, finb);

        // 4. c1 & f1 dual
        gemm_dualg<<<dim3(8, 32, 2), 256, 0, stream>>>(
            pzb, 64, 64, finb, 256, 256, cW1T, 64, fW1T, 256, cb1, fb1, h1c, h1f);
        // 5. c2 & f2 dual
        gemm_dualg<<<dim3(8, 32, 2), 256, 0, stream>>>(
            h1c, 1024, 1024, h1f, 1024, 1024, cW2T, 1024, fW2T, 1024, cb2, fb2, h2c, h2fb);

        // 6. c3 + f3 partials, 7. fused reduce
        part_cf3_k<<<dim3(2, 32, 12), 256, 0, stream>>>(
            h2c, cW3T, h2fb, fW3T, part_c3, part_f3);
        red_cf3_k<<<dim3(1280), 256, 0, stream>>>(
            part_c3, cb3, ctxb, part_f3, fb3, flat);

        // 8. g-net (2 elems/thread, r8 config) || Ah concat
        tail_k<<<dim3(5912), 256, 0, stream>>>(
            flat, gW1, b1s, w2s, gb2, ctxb, Ah, out);

        // 9. heads GEMM with fused final epilogue
        gemm_heads_k<<<dim3(32), 256, 0, stream>>>(Ah, WhcT, ctxb, out);
    } else {
        // -------- fallback: r6 structure (known-good) --------
        const dim3 tb(32, 8);
        transpose_w<<<dim3(32, 2),  tb, 0, stream>>>(cW1, cW1T, 64, 1024, 64, 1024);
        transpose_w<<<dim3(32, 32), tb, 0, stream>>>(cW2, cW2T, 1024, 1024, 1024, 1024);
        transpose_w<<<dim3(4, 32),  tb, 0, stream>>>(cW3, cW3T, 1024, 64, 1024, 128);
        transpose_w<<<dim3(32, 8),  tb, 0, stream>>>(fW1, fW1T, 227, 1024, 256, 1024);
        transpose_w<<<dim3(32, 32), tb, 0, stream>>>(fW2, fW2T, 1024, 1024, 1024, 1024);
        transpose_w<<<dim3(8, 32),  tb, 0, stream>>>(fW3, fW3T, 1024, 227, 1024, 256);
        wcat_t<<<dim3(8, 181), tb, 0, stream>>>(Wref, WcatT);
        gscale_k<<<dim3(202), 256, 0, stream>>>(gb1, gW2, b1s, w2s);
        fillb_k<<<dim3(1, M), 256, 0, stream>>>(fin, nullptr, 228, 0);
        fillb_k<<<dim3(1, M), 256, 0, stream>>>(flat, fb3, 228, 227);
        fillb_k<<<dim3(1, M), 256, 0, stream>>>(ctxb, cb3, 64, 64);
        unsigned short* h1 = h1fb;
        gemm_mfma<0, 1, false, true><<<dim3(8, 32, 1), 256, 0, stream>>>(
            pz, 64, nullptr, cW1T, 64, cb1, h1, 1024, M, 1024, 64, 64);
        gemm_mfma<1, 1, false, true><<<dim3(8, 32, 1), 256, 0, stream>>>(
            h1, 1024, nullptr, cW2T, 1024, cb2, h2b, 1024, M, 1024, 1024, 1024);
        gemm_mfma<1, 0, true, false><<<dim3(1, 32, 8), 256, 0, stream>>>(
            h2b, 1024, nullptr, cW3T, 1024, nullptr, ctxb, 64, M, 64, 1024, 128);
        gemm_mfma<2, 0, true, false><<<dim3(2, 32, 8), 256, 0, stream>>>(
            se, 5705, pz, WcatT, 5792, nullptr, fin, 228, M, 227, 5769, 736);
        gemm_mfma<0, 1, false, true><<<dim3(8, 32, 1), 256, 0, stream>>>(
            fin, 228, nullptr, fW1T, 256, fb1, h1, 1024, M, 1024, 227, 227);
        gemm_mfma<1, 1, false, true><<<dim3(8, 32, 1), 256, 0, stream>>>(
            h1, 1024, nullptr, fW2T, 1024, fb2, h2b, 1024, M, 1024, 1024, 1024);
        gemm_mfma<1, 0, true, false><<<dim3(2, 32, 8), 256, 0, stream>>>(
            h2b, 1024, nullptr, fW3T, 1024, nullptr, flat, 228, M, 227, 1024, 128);
        heads_k<<<dim3(4096), 256, 0, stream>>>(flat, ctxb, Wland, Wshot, Wmove,
                                                cWl, cWs, cWm, out);
        g_kernel2<<<dim3(227, 8), 256, 0, stream>>>(flat, gW1, b1s, w2s, gb2, out);
    }
}

// Round 11
// 378.732 us; speedup vs baseline: 1.1456x; 1.1456x over previous
//
#include <hip/hip_runtime.h>
#include <hip/hip_bf16.h>

using s8 = __attribute__((ext_vector_type(8))) short;
using f4 = __attribute__((ext_vector_type(4))) float;
using us8 = __attribute__((ext_vector_type(8))) unsigned short;

__device__ __forceinline__ void glds16(const void* g, void* l) {
    __builtin_amdgcn_global_load_lds(
        (const __attribute__((address_space(1))) void*)g,
        (__attribute__((address_space(3))) void*)l, 16, 0, 0);
}

__device__ __forceinline__ unsigned short f2b(float f) {
    union { float f; unsigned u; } v; v.f = f;
    unsigned r = v.u + 0x7fffu + ((v.u >> 16) & 1u);
    return (unsigned short)(r >> 16);
}
__device__ __forceinline__ float softplus_f(float x) {
    return fmaxf(x, 0.f) + __logf(1.f + __expf(-fabsf(x)));
}
__device__ __forceinline__ float sigmoid_f(float x) {
    return 1.f / (1.f + __expf(-x));
}
__device__ __forceinline__ float exp2_f(float x) {
    float r; asm("v_exp_f32 %0, %1" : "=v"(r) : "v"(x)); return r;
}
__device__ __forceinline__ float log2_f(float x) {
    float r; asm("v_log_f32 %0, %1" : "=v"(r) : "v"(x)); return r;
}

__device__ __forceinline__ float lse12(const float* s) {
    float m = s[0];
#pragma unroll
    for (int j = 1; j < 12; j++) m = fmaxf(m, s[j]);
    float sum = 0.f;
#pragma unroll
    for (int j = 0; j < 12; j++) sum += __expf(s[j] - m);
    return m + __logf(sum);
}

// ---------------------------------------------------------------------------
// prep_all_k: ALL input-only prep in one launch. 256 threads. Block ranges:
//   [0,2752)      6 weight transposes (f32->bf16, zero-padded)
//   [2752,4200)   WcatT (8 x 181 tiles)
//   [4200,5586)   flat misc: pz->pzb | gscale | WhcT
//   [5586,17874)  Acat concat (3 x 4096)
// ---------------------------------------------------------------------------
__global__ __launch_bounds__(256) void prep_all_k(
    const float* __restrict__ cW1, const float* __restrict__ cW2,
    const float* __restrict__ cW3, const float* __restrict__ fW1,
    const float* __restrict__ fW2, const float* __restrict__ fW3,
    unsigned short* __restrict__ cW1T, unsigned short* __restrict__ cW2T,
    unsigned short* __restrict__ cW3T, unsigned short* __restrict__ fW1T,
    unsigned short* __restrict__ fW2T, unsigned short* __restrict__ fW3T,
    const float* __restrict__ Wref, unsigned short* __restrict__ WcatT,
    const float* __restrict__ pz, unsigned short* __restrict__ pzb,
    const float* __restrict__ gb1, const float* __restrict__ gW2,
    float* __restrict__ b1s, float* __restrict__ w2s,
    const float* __restrict__ Wl, const float* __restrict__ Ws,
    const float* __restrict__ Wm, const float* __restrict__ cWl,
    const float* __restrict__ cWs, const float* __restrict__ cWm,
    unsigned short* __restrict__ WhcT,
    const float* __restrict__ se, unsigned short* __restrict__ Acat) {
    __shared__ float tile[32][33];
    const int b = blockIdx.x, t = threadIdx.x;
    if (b < 2752) {
        // ---- 6 transposes ----
        int z, r = b;
        if (r < 64) { z = 0; }
        else if (r < 1088) { z = 1; r -= 64; }
        else if (r < 1216) { z = 2; r -= 1088; }
        else if (r < 1472) { z = 3; r -= 1216; }
        else if (r < 2496) { z = 4; r -= 1472; }
        else { z = 5; r -= 2496; }
        const float* src = z == 0 ? cW1 : z == 1 ? cW2 : z == 2 ? cW3
                          : z == 3 ? fW1 : z == 4 ? fW2 : fW3;
        unsigned short* dst = z == 0 ? cW1T : z == 1 ? cW2T : z == 2 ? cW3T
                             : z == 3 ? fW1T : z == 4 ? fW2T : fW3T;
        const int K    = z == 0 ? 64 : z == 3 ? 227 : 1024;
        const int N    = z == 2 ? 64 : z == 5 ? 227 : 1024;
        const int Kpad = z == 0 ? 64 : z == 3 ? 256 : 1024;
        const int Npad = z == 2 ? 128 : z == 5 ? 256 : 1024;
        const int nbx = Npad >> 5;
        const int bx = r % nbx, by = r / nbx;
        const int n0 = bx * 32, k0 = by * 32;
        const int tx = t & 31, ty = t >> 5;
#pragma unroll
        for (int rr = 0; rr < 4; rr++) {
            int k = k0 + ty + rr * 8, n = n0 + tx;
            tile[ty + rr * 8][tx] = (k < K && n < N) ? src[(size_t)k * N + n] : 0.f;
        }
        __syncthreads();
#pragma unroll
        for (int rr = 0; rr < 4; rr++) {
            int n = n0 + ty + rr * 8, k = k0 + tx;
            dst[(size_t)n * Kpad + k] = f2b(tile[tx][ty + rr * 8]);
        }
    } else if (b < 4200) {
        // ---- WcatT ----
        const int r = b - 2752;
        const int n0 = (r & 7) * 32, k0 = (r >> 3) * 32;
        const int tx = t & 31, ty = t >> 5;
#pragma unroll
        for (int rr = 0; rr < 4; rr++) {
            int k = k0 + ty + rr * 8, n = n0 + tx;
            float v = 0.f;
            if (n < 227 && k < 5769) {
                if (k < 5705) {
                    int wrow = k + 64 * (k / 163);
                    v = Wref[(size_t)wrow * 227 + n];
                } else {
                    int j2 = k - 5705;
                    for (int tt = 0; tt < 35; tt++)
                        v += Wref[(size_t)(tt * 227 + 163 + j2) * 227 + n];
                }
            }
            tile[ty + rr * 8][tx] = v;
        }
        __syncthreads();
#pragma unroll
        for (int rr = 0; rr < 4; rr++) {
            int n = n0 + ty + rr * 8, k = k0 + tx;
            if (n < 256 && k < 5792)
                WcatT[(size_t)n * 5792 + k] = f2b(tile[tx][ty + rr * 8]);
        }
    } else if (b < 5586) {
        // ---- misc flat: pz cvt | gscale | WhcT ----
        constexpr int NCVT = 4096 * 64;
        constexpr int NGS = 227 * 227;
        constexpr int NW = 128 * 320;
        int i = (b - 4200) * 256 + t;
        if (i < NCVT) {
            pzb[i] = f2b(pz[i]);
        } else if (i < NCVT + NGS) {
            int j = i - NCVT;
            b1s[j] = gb1[j] * 1.44269504f;
            w2s[j] = gW2[j] * 0.69314718f;
        } else if (i < NCVT + NGS + NW) {
            int j = i - NCVT - NGS;
            int n = j / 320, k = j - n * 320;
            float v = 0.f;
            if (n < 62 && k < 227) {
                if (n < 25)      v = Wl[(size_t)k * 25 + n];
                else if (n < 37) v = Ws[(size_t)k * 12 + (n - 25)];
                else             v = Wm[(size_t)k * 25 + (n - 37)];
            } else if (n >= 64 && n < 126 && k >= 256) {
                const int jj = n - 64, kk = k - 256;
                if (jj < 25)      v = cWl[(size_t)kk * 25 + jj];
                else if (jj < 37) v = cWs[(size_t)kk * 12 + (jj - 25)];
                else              v = cWm[(size_t)kk * 25 + (jj - 37)];
            }
            WhcT[(size_t)n * 320 + k] = f2b(v);
        }
    } else {
        // ---- Acat concat, 8 cols/thread, ushort8 stores ----
        const int r = b - 5586;
        const int c = (r % 3) * 256 + t;
        const int row = r / 3;
        if (c >= 724) return;
        const int col0 = c * 8;
        us8 o;
        if (col0 + 8 <= 5705) {
            const float* s = se + (size_t)row * 5705 + col0;
#pragma unroll
            for (int j = 0; j < 8; j++) o[j] = f2b(s[j]);
        } else {
#pragma unroll
            for (int j = 0; j < 8; j++) {
                int col = col0 + j;
                float v = 0.f;
                if (col < 5705) v = se[(size_t)row * 5705 + col];
                else if (col < 5769) v = pz[(size_t)row * 64 + (col - 5705)];
                o[j] = f2b(v);
            }
        }
        *(us8*)(Acat + (size_t)row * 5792 + col0) = o;
    }
}

// ---------------------------------------------------------------------------
// red_enc4: finb = bf16(sum_{z<6} part_enc), float4 loads. grid (1,1024).
// ---------------------------------------------------------------------------
__global__ __launch_bounds__(256) void red_enc4(const float* __restrict__ part,
                                                unsigned short* __restrict__ finb) {
    const int t = threadIdx.x;
    const int row = blockIdx.y * 4 + (t >> 6);
    const int cw = t & 63;
    if (cw < 57) {
        const float* p = part + (size_t)row * 228 + cw * 4;
        float4 s = make_float4(0.f, 0.f, 0.f, 0.f);
#pragma unroll
        for (int z = 0; z < 6; z++) {
            float4 v = *(const float4*)(p + (size_t)z * 4096 * 228);
            s.x += v.x; s.y += v.y; s.z += v.z; s.w += v.w;
        }
        if (cw == 56) s.w = 0.f;
        ushort4 o;
        o.x = f2b(s.x); o.y = f2b(s.y); o.z = f2b(s.z); o.w = f2b(s.w);
        *(ushort4*)(finb + (size_t)row * 256 + cw * 4) = o;
    } else {
        ushort4 z4 = make_ushort4(0, 0, 0, 0);
        *(ushort4*)(finb + (size_t)row * 256 + 228 + (cw - 57) * 4) = z4;
    }
}

// ---------------------------------------------------------------------------
// red_cf3_k: fused c3 + f3 partial reduction. grid (1280), block 256.
// ---------------------------------------------------------------------------
__global__ __launch_bounds__(256) void red_cf3_k(
    const float* __restrict__ part_c3, const float* __restrict__ cb3,
    float* __restrict__ ctxb,
    const float* __restrict__ part_f3, const float* __restrict__ fb3,
    float* __restrict__ flat) {
    const int bx = blockIdx.x, t = threadIdx.x;
    if (bx < 256) {
        int idx = bx * 256 + t;
        int row = idx >> 4, c4 = idx & 15;
        float4 s = *(const float4*)(cb3 + c4 * 4);
        const float* p = part_c3 + (size_t)row * 64 + c4 * 4;
#pragma unroll
        for (int z = 0; z < 8; z++) {
            float4 v = *(const float4*)(p + (size_t)z * 4096 * 64);
            s.x += v.x; s.y += v.y; s.z += v.z; s.w += v.w;
        }
        *(float4*)(ctxb + (size_t)row * 64 + c4 * 4) = s;
    } else {
        const int by = bx - 256;
        const int row = by * 4 + (t >> 6);
        const int cw = t & 63;
        if (cw >= 57) return;
        float b[4];
#pragma unroll
        for (int j = 0; j < 4; j++) {
            int col = cw * 4 + j;
            b[j] = (col < 227) ? fb3[col] : 0.f;
        }
        const float* p = part_f3 + (size_t)row * 228 + cw * 4;
        float4 s = make_float4(b[0], b[1], b[2], b[3]);
#pragma unroll
        for (int z = 0; z < 4; z++) {
            float4 v = *(const float4*)(p + (size_t)z * 4096 * 228);
            s.x += v.x; s.y += v.y; s.z += v.z; s.w += v.w;
        }
        if (cw == 56) s.w = 0.f;
        *(float4*)(flat + (size_t)row * 228 + cw * 4) = s;
    }
}

// ---------------------------------------------------------------------------
// m97-style DMA GEMM. CM: 0=store(+bias/act), 2=partial f32 (slice stride 4096*ldc)
// ---------------------------------------------------------------------------
template <int CM, int ACT, bool OBF16>
__global__ __launch_bounds__(256) void gemm_dma(
    const unsigned short* __restrict__ A, int lda,
    const unsigned short* __restrict__ WT, int ldwt,
    const float* __restrict__ bias,
    void* __restrict__ Cptr, int ldc, int N, int K, int kchunk) {
    __shared__ __align__(16) unsigned short As[128 * 32];
    __shared__ __align__(16) unsigned short Bs[128 * 32];
    const int tid = threadIdx.x;
    const int m0 = blockIdx.y * 128, n0 = blockIdx.x * 128;
    const int kbeg = blockIdx.z * kchunk;
    const int kend = min(kbeg + kchunk, K);
    const int lane = tid & 63, w = tid >> 6;
    const int wm = w >> 1, wn = w & 1;
    const int quad = lane >> 4, l16 = lane & 15;
    const int dr = lane >> 2;
    const int dk = (lane & 3) * 8;

    f4 acc[4][4] = {};

    for (int k0 = kbeg; k0 < kend; k0 += 32) {
#pragma unroll
        for (int c = 0; c < 2; c++) {
            int rr = w * 32 + c * 16;
            glds16(A + (size_t)(m0 + rr + dr) * lda + k0 + dk, &As[rr * 32]);
            glds16(WT + (size_t)(n0 + rr + dr) * ldwt + k0 + dk, &Bs[rr * 32]);
        }
        __syncthreads();
        s8 a[4], b[4];
#pragma unroll
        for (int mi = 0; mi < 4; mi++)
            a[mi] = *(const s8*)&As[(wm * 64 + mi * 16 + l16) * 32 + quad * 8];
#pragma unroll
        for (int ni = 0; ni < 4; ni++)
            b[ni] = *(const s8*)&Bs[(wn * 64 + ni * 16 + l16) * 32 + quad * 8];
#pragma unroll
        for (int mi = 0; mi < 4; mi++)
#pragma unroll
            for (int ni = 0; ni < 4; ni++)
                acc[mi][ni] = __builtin_amdgcn_mfma_f32_16x16x32_bf16(
                    a[mi], b[ni], acc[mi][ni], 0, 0, 0);
        __syncthreads();
    }

    const size_t zoff = (CM == 2) ? (size_t)blockIdx.z * 4096 * ldc : 0;
#pragma unroll
    for (int mi = 0; mi < 4; mi++) {
        int gmb = m0 + wm * 64 + mi * 16 + quad * 4;
#pragma unroll
        for (int ni = 0; ni < 4; ni++) {
            int gn = n0 + wn * 64 + ni * 16 + l16;
            if (gn < N) {
#pragma unroll
                for (int r = 0; r < 4; r++) {
                    float v = acc[mi][ni][r];
                    size_t off = (size_t)(gmb + r) * ldc + gn;
                    if (CM == 2) {
                        ((float*)Cptr)[zoff + off] = v;
                    } else {
                        if (bias) v += bias[gn];
                        if (ACT == 1) v = softplus_f(v);
                        if (OBF16) ((unsigned short*)Cptr)[off] = f2b(v);
                        else ((float*)Cptr)[off] = v;
                    }
                }
            }
        }
    }
}

// ---------------------------------------------------------------------------
// gemm_dualg: dual-problem GEMM, per-z (A,lda,K,W,ldw,bias,C). N=1024, ldc=1024,
// out bf16(softplus(.+bias)). grid (8,32,2).
// ---------------------------------------------------------------------------
__global__ __launch_bounds__(256) void gemm_dualg(
    const unsigned short* __restrict__ A0, int lda0, int K0,
    const unsigned short* __restrict__ A1, int lda1, int K1,
    const unsigned short* __restrict__ W0, int ldw0,
    const unsigned short* __restrict__ W1, int ldw1,
    const float* __restrict__ b0, const float* __restrict__ b1,
    unsigned short* __restrict__ C0, unsigned short* __restrict__ C1) {
    __shared__ __align__(16) unsigned short As[128 * 32];
    __shared__ __align__(16) unsigned short Bs[128 * 32];
    const int z = blockIdx.z;
    const unsigned short* __restrict__ A  = z ? A1 : A0;
    const unsigned short* __restrict__ WT = z ? W1 : W0;
    const float* __restrict__ bias        = z ? b1 : b0;
    unsigned short* __restrict__ C        = z ? C1 : C0;
    const int lda = z ? lda1 : lda0;
    const int ldw = z ? ldw1 : ldw0;
    const int K   = z ? K1 : K0;
    const int tid = threadIdx.x;
    const int m0 = blockIdx.y * 128, n0 = blockIdx.x * 128;
    const int lane = tid & 63, w = tid >> 6;
    const int wm = w >> 1, wn = w & 1;
    const int quad = lane >> 4, l16 = lane & 15;
    const int dr = lane >> 2;
    const int dk = (lane & 3) * 8;

    f4 acc[4][4] = {};

    for (int k0 = 0; k0 < K; k0 += 32) {
#pragma unroll
        for (int c = 0; c < 2; c++) {
            int rr = w * 32 + c * 16;
            glds16(A + (size_t)(m0 + rr + dr) * lda + k0 + dk, &As[rr * 32]);
            glds16(WT + (size_t)(n0 + rr + dr) * ldw + k0 + dk, &Bs[rr * 32]);
        }
        __syncthreads();
        s8 a[4], b[4];
#pragma unroll
        for (int mi = 0; mi < 4; mi++)
            a[mi] = *(const s8*)&As[(wm * 64 + mi * 16 + l16) * 32 + quad * 8];
#pragma unroll
        for (int ni = 0; ni < 4; ni++)
            b[ni] = *(const s8*)&Bs[(wn * 64 + ni * 16 + l16) * 32 + quad * 8];
#pragma unroll
        for (int mi = 0; mi < 4; mi++)
#pragma unroll
            for (int ni = 0; ni < 4; ni++)
                acc[mi][ni] = __builtin_amdgcn_mfma_f32_16x16x32_bf16(
                    a[mi], b[ni], acc[mi][ni], 0, 0, 0);
        __syncthreads();
    }

#pragma unroll
    for (int mi = 0; mi < 4; mi++) {
        int gmb = m0 + wm * 64 + mi * 16 + quad * 4;
#pragma unroll
        for (int ni = 0; ni < 4; ni++) {
            int gn = n0 + wn * 64 + ni * 16 + l16;
#pragma unroll
            for (int r = 0; r < 4; r++) {
                float v = acc[mi][ni][r] + bias[gn];
                C[(size_t)(gmb + r) * 1024 + gn] = f2b(softplus_f(v));
            }
        }
    }
}

// ---------------------------------------------------------------------------
// part_cf3_k: fused c3 (z<8) + f3 (z>=8) split-K partial GEMMs. grid (2,32,12).
// ---------------------------------------------------------------------------
__global__ __launch_bounds__(256) void part_cf3_k(
    const unsigned short* __restrict__ h2c, const unsigned short* __restrict__ cW3T,
    const unsigned short* __restrict__ h2f, const unsigned short* __restrict__ fW3T,
    float* __restrict__ part_c3, float* __restrict__ part_f3) {
    __shared__ __align__(16) unsigned short As[128 * 32];
    __shared__ __align__(16) unsigned short Bs[128 * 32];
    const int z = blockIdx.z;
    const bool isC = (z < 8);
    if (isC && blockIdx.x != 0) return;
    const unsigned short* __restrict__ A  = isC ? h2c : h2f;
    const unsigned short* __restrict__ WT = isC ? cW3T : fW3T;
    const int N   = isC ? 64 : 227;
    const int ldc = isC ? 64 : 228;
    const int zz  = isC ? z : z - 8;
    const int kbeg = zz * (isC ? 128 : 256);
    const int kend = kbeg + (isC ? 128 : 256);
    float* __restrict__ C = (isC ? part_c3 : part_f3) + (size_t)zz * 4096 * ldc;
    const int tid = threadIdx.x;
    const int m0 = blockIdx.y * 128, n0 = blockIdx.x * 128;
    const int lane = tid & 63, w = tid >> 6;
    const int wm = w >> 1, wn = w & 1;
    const int quad = lane >> 4, l16 = lane & 15;
    const int dr = lane >> 2;
    const int dk = (lane & 3) * 8;

    f4 acc[4][4] = {};

    for (int k0 = kbeg; k0 < kend; k0 += 32) {
#pragma unroll
        for (int c = 0; c < 2; c++) {
            int rr = w * 32 + c * 16;
            glds16(A + (size_t)(m0 + rr + dr) * 1024 + k0 + dk, &As[rr * 32]);
            glds16(WT + (size_t)(n0 + rr + dr) * 1024 + k0 + dk, &Bs[rr * 32]);
        }
        __syncthreads();
        s8 a[4], b[4];
#pragma unroll
        for (int mi = 0; mi < 4; mi++)
            a[mi] = *(const s8*)&As[(wm * 64 + mi * 16 + l16) * 32 + quad * 8];
#pragma unroll
        for (int ni = 0; ni < 4; ni++)
            b[ni] = *(const s8*)&Bs[(wn * 64 + ni * 16 + l16) * 32 + quad * 8];
#pragma unroll
        for (int mi = 0; mi < 4; mi++)
#pragma unroll
            for (int ni = 0; ni < 4; ni++)
                acc[mi][ni] = __builtin_amdgcn_mfma_f32_16x16x32_bf16(
                    a[mi], b[ni], acc[mi][ni], 0, 0, 0);
        __syncthreads();
    }

#pragma unroll
    for (int mi = 0; mi < 4; mi++) {
        int gmb = m0 + wm * 64 + mi * 16 + quad * 4;
#pragma unroll
        for (int ni = 0; ni < 4; ni++) {
            int gn = n0 + wn * 64 + ni * 16 + l16;
            if (gn < N) {
#pragma unroll
                for (int r = 0; r < 4; r++)
                    C[(size_t)(gmb + r) * ldc + gn] = acc[mi][ni][r];
            }
        }
    }
}

// ---------------------------------------------------------------------------
// tail_k: g-net (blocks 0..1815) || Ah concat (blocks 1816..5911). block 256.
// ---------------------------------------------------------------------------
__global__ __launch_bounds__(256) void tail_k(
    const float* __restrict__ flat,
    const float* __restrict__ gW1, const float* __restrict__ b1s,
    const float* __restrict__ w2s, const float* __restrict__ gb2,
    const float* __restrict__ ctxb, unsigned short* __restrict__ Ah,
    float* __restrict__ out) {
    __shared__ float4 wt[228];
    const int bid = blockIdx.x, t = threadIdx.x;
    if (bid < 1816) {
        const int d = bid >> 3;          // 0..226
        const int y = bid & 7;
        if (t < 227) {
            size_t o = (size_t)d * 227 + t;
            wt[t] = make_float4(gW1[o], b1s[o], w2s[o], 0.f);
        } else if (t == 227) {
            wt[227] = make_float4(0.f, 0.f, 0.f, 0.f);
        }
        __syncthreads();
        const int b0 = y * 512 + t;
        float x0 = flat[(size_t)b0 * 228 + d] * 1.44269504f;
        float x1 = flat[(size_t)(b0 + 256) * 228 + d] * 1.44269504f;
        const float g2 = gb2[d];
        float a0 = g2, a1 = g2;
        float4 w = wt[0];
#pragma unroll 2
        for (int h = 0; h < 227; h++) {
            float4 wn = wt[h + 1];
            float z0 = fmaf(x0, w.x, w.y);
            float z1 = fmaf(x1, w.x, w.y);
            a0 = fmaf(log2_f(1.f + exp2_f(z0)), w.z, a0);
            a1 = fmaf(log2_f(1.f + exp2_f(z1)), w.z, a1);
            w = wn;
        }
        out[(size_t)b0 * 415 + 62 + d] = sigmoid_f(a0);
        out[(size_t)(b0 + 256) * 415 + 62 + d] = sigmoid_f(a1);
    } else {
        const int row = bid - 1816;
        float v = 0.f;
        if (t < 227) v = flat[(size_t)row * 228 + t];
        Ah[(size_t)row * 320 + t] = f2b(v);            // cols 0..255
        if (t < 64) Ah[(size_t)row * 320 + 256 + t] = f2b(ctxb[(size_t)row * 64 + t]);
    }
}

// ---------------------------------------------------------------------------
// gemm_heads_k: heads GEMM (M=4096, N=126, K=320) with fused final epilogue.
// grid (32), block 256.
// ---------------------------------------------------------------------------
__global__ __launch_bounds__(256) void gemm_heads_k(
    const unsigned short* __restrict__ Ah, const unsigned short* __restrict__ WhcT,
    const float* __restrict__ ctxb, float* __restrict__ out) {
    __shared__ __align__(16) unsigned short As[128 * 32];
    __shared__ __align__(16) unsigned short Bs[128 * 32];
    __shared__ float cT[64][129];
    const int tid = threadIdx.x;
    const int m0 = blockIdx.x * 128;
    const int lane = tid & 63, w = tid >> 6;
    const int wm = w >> 1, wn = w & 1;
    const int quad = lane >> 4, l16 = lane & 15;
    const int dr = lane >> 2;
    const int dk = (lane & 3) * 8;

    f4 acc[4][4] = {};

    for (int k0 = 0; k0 < 320; k0 += 32) {
#pragma unroll
        for (int c = 0; c < 2; c++) {
            int rr = w * 32 + c * 16;
            glds16(Ah + (size_t)(m0 + rr + dr) * 320 + k0 + dk, &As[rr * 32]);
            glds16(WhcT + (size_t)(rr + dr) * 320 + k0 + dk, &Bs[rr * 32]);
        }
        __syncthreads();
        s8 a[4], b[4];
#pragma unroll
        for (int mi = 0; mi < 4; mi++)
            a[mi] = *(const s8*)&As[(wm * 64 + mi * 16 + l16) * 32 + quad * 8];
#pragma unroll
        for (int ni = 0; ni < 4; ni++)
            b[ni] = *(const s8*)&Bs[(wn * 64 + ni * 16 + l16) * 32 + quad * 8];
#pragma unroll
        for (int mi = 0; mi < 4; mi++)
#pragma unroll
            for (int ni = 0; ni < 4; ni++)
                acc[mi][ni] = __builtin_amdgcn_mfma_f32_16x16x32_bf16(
                    a[mi], b[ni], acc[mi][ni], 0, 0, 0);
        __syncthreads();
    }

#pragma unroll
    for (int pass = 0; pass < 2; pass++) {
        if (wm == pass) {
#pragma unroll
            for (int mi = 0; mi < 4; mi++) {
                int rl = mi * 16 + quad * 4;
#pragma unroll
                for (int ni = 0; ni < 4; ni++) {
                    int cl = wn * 64 + ni * 16 + l16;
#pragma unroll
                    for (int r = 0; r < 4; r++)
                        cT[rl + r][cl] = acc[mi][ni][r];
                }
            }
        }
        __syncthreads();
        if (tid < 64) {
            const int bidx = m0 + pass * 64 + tid;
            float* ob = out + (size_t)bidx * 415;
            const float* row = cT[tid];
            float sraw[12], craw[12];
#pragma unroll
            for (int j = 0; j < 25; j++) ob[j] = row[j];
#pragma unroll
            for (int j = 0; j < 12; j++) sraw[j] = row[25 + j];
#pragma unroll
            for (int j = 0; j < 25; j++) ob[37 + j] = row[37 + j];
#pragma unroll
            for (int j = 0; j < 25; j++) ob[289 + j] = row[64 + j];
#pragma unroll
            for (int j = 0; j < 12; j++) craw[j] = row[89 + j];
#pragma unroll
            for (int j = 0; j < 25; j++) ob[326 + j] = row[101 + j];
            const float lsf = lse12(sraw), lsc = lse12(craw);
#pragma unroll
            for (int j = 0; j < 12; j++) {
                ob[25 + j] = sraw[j] - lsf;
                ob[314 + j] = craw[j] - lsc;
            }
            for (int k = 0; k < 64; k++)
                ob[351 + k] = ctxb[(size_t)bidx * 64 + k];
        }
        __syncthreads();
    }
}

// ---------------------------------------------------------------------------
// ---------------- FALLBACK path kernels (r6 known-good) --------------------
// ---------------------------------------------------------------------------
__global__ __launch_bounds__(256) void transpose_w(const float* __restrict__ src,
                                                   unsigned short* __restrict__ dst,
                                                   int K, int N, int Kpad, int Npad) {
    __shared__ float tile[32][33];
    const int n0 = blockIdx.x * 32, k0 = blockIdx.y * 32;
    const int tx = threadIdx.x, ty = threadIdx.y;
#pragma unroll
    for (int r = 0; r < 4; r++) {
        int k = k0 + ty + r * 8, n = n0 + tx;
        tile[ty + r * 8][tx] = (k < K && n < N) ? src[(size_t)k * N + n] : 0.f;
    }
    __syncthreads();
#pragma unroll
    for (int r = 0; r < 4; r++) {
        int n = n0 + ty + r * 8, k = k0 + tx;
        if (n < Npad && k < Kpad) dst[(size_t)n * Kpad + k] = f2b(tile[tx][ty + r * 8]);
    }
}

__global__ __launch_bounds__(256) void wcat_t(const float* __restrict__ Wref,
                                              unsigned short* __restrict__ dst) {
    __shared__ float tile[32][33];
    const int n0 = blockIdx.x * 32, k0 = blockIdx.y * 32;
    const int tx = threadIdx.x, ty = threadIdx.y;
#pragma unroll
    for (int r = 0; r < 4; r++) {
        int k = k0 + ty + r * 8, n = n0 + tx;
        float v = 0.f;
        if (n < 227 && k < 5769) {
            if (k < 5705) {
                int wrow = k + 64 * (k / 163);
                v = Wref[(size_t)wrow * 227 + n];
            } else {
                int j2 = k - 5705;
                for (int t = 0; t < 35; t++)
                    v += Wref[(size_t)(t * 227 + 163 + j2) * 227 + n];
            }
        }
        tile[ty + r * 8][tx] = v;
    }
    __syncthreads();
#pragma unroll
    for (int r = 0; r < 4; r++) {
        int n = n0 + ty + r * 8, k = k0 + tx;
        if (n < 256 && k < 5792) dst[(size_t)n * 5792 + k] = f2b(tile[tx][ty + r * 8]);
    }
}

__global__ __launch_bounds__(256) void gscale_k(const float* __restrict__ gb1,
                                                const float* __restrict__ gW2,
                                                float* __restrict__ b1s,
                                                float* __restrict__ w2s) {
    int i = blockIdx.x * 256 + threadIdx.x;
    if (i < 227 * 227) {
        b1s[i] = gb1[i] * 1.44269504f;
        w2s[i] = gW2[i] * 0.69314718f;
    }
}

__global__ __launch_bounds__(256) void fillb_k(float* __restrict__ buf,
                                               const float* __restrict__ bias,
                                               int ld, int ncr) {
    const int row = blockIdx.y;
    const int col = blockIdx.x * 256 + threadIdx.x;
    if (col >= ld) return;
    float v = 0.f;
    if (bias && col < ncr) v = bias[col];
    buf[(size_t)row * ld + col] = v;
}

template <int AMODE, int ACT, bool ATOMIC, bool OBF16>
__global__ __launch_bounds__(256) void gemm_mfma(
    const void* __restrict__ Aptr, int lda,
    const float* __restrict__ A2ptr,
    const unsigned short* __restrict__ WT, int ldwt,
    const float* __restrict__ bias,
    void* __restrict__ Cptr, int ldc,
    int M, int N, int K, int kchunk) {
    __shared__ unsigned short As[128 * 40];
    __shared__ unsigned short Bs[128 * 40];
    const int tid = threadIdx.x;
    const int m0 = blockIdx.y * 128, n0 = blockIdx.x * 128;
    const int kbeg = blockIdx.z * kchunk;
    const int kend = min(kbeg + kchunk, K);
    const int lane = tid & 63, w = tid >> 6;
    const int wm = w >> 1, wn = w & 1;
    const int quad = lane >> 4, l16 = lane & 15;

    f4 acc[4][4] = {};
    ushort4 pa[4], pb[4];

    auto loadA = [&](int k0) {
        const bool full = (kend - k0) >= 32;
#pragma unroll
        for (int i = 0; i < 4; i++) {
            int f = tid + i * 256;
            int r = f >> 3, cc = (f & 7) * 4;
            int gm = m0 + r;
            ushort4 val;
            if (AMODE == 0) {
                const float* A = (const float*)Aptr;
                float t[4];
#pragma unroll
                for (int j = 0; j < 4; j++) {
                    int k = k0 + cc + j;
                    t[j] = (k < kend) ? A[(size_t)gm * lda + k] : 0.f;
                }
                val.x = f2b(t[0]); val.y = f2b(t[1]); val.z = f2b(t[2]); val.w = f2b(t[3]);
            } else if (AMODE == 1) {
                const unsigned short* A = (const unsigned short*)Aptr;
                if (full) {
                    val = *(const ushort4*)(A + (size_t)gm * lda + k0 + cc);
                } else {
                    unsigned short t[4];
#pragma unroll
                    for (int j = 0; j < 4; j++) {
                        int k = k0 + cc + j;
                        t[j] = (k < kend) ? A[(size_t)gm * lda + k] : (unsigned short)0;
                    }
                    val.x = t[0]; val.y = t[1]; val.z = t[2]; val.w = t[3];
                }
            } else {
                const float* se = (const float*)Aptr;
                float t[4];
#pragma unroll
                for (int j = 0; j < 4; j++) {
                    int k = k0 + cc + j;
                    float v = 0.f;
                    if (k < kend) {
                        v = (k < 5705) ? se[(size_t)gm * 5705 + k]
                                       : A2ptr[(size_t)gm * 64 + (k - 5705)];
                    }
                    t[j] = v;
                }
                val.x = f2b(t[0]); val.y = f2b(t[1]); val.z = f2b(t[2]); val.w = f2b(t[3]);
            }
            pa[i] = val;
        }
    };
    auto loadB = [&](int k0) {
        const bool full = (kend - k0) >= 32;
#pragma unroll
        for (int i = 0; i < 4; i++) {
            int f = tid + i * 256;
            int r = f >> 3, cc = (f & 7) * 4;
            int gn = n0 + r;
            ushort4 val;
            if (gn < N) {
                if (full) {
                    val = *(const ushort4*)(WT + (size_t)gn * ldwt + k0 + cc);
                } else {
                    unsigned short t[4];
#pragma unroll
                    for (int j = 0; j < 4; j++) {
                        int k = k0 + cc + j;
                        t[j] = (k < kend) ? WT[(size_t)gn * ldwt + k] : (unsigned short)0;
                    }
                    val.x = t[0]; val.y = t[1]; val.z = t[2]; val.w = t[3];
                }
            } else {
                val.x = val.y = val.z = val.w = 0;
            }
            pb[i] = val;
        }
    };

    loadA(kbeg); loadB(kbeg);
    for (int k0 = kbeg; k0 < kend; k0 += 32) {
#pragma unroll
        for (int i = 0; i < 4; i++) {
            int f = tid + i * 256;
            int r = f >> 3, cc = (f & 7) * 4;
            *(ushort4*)&As[r * 40 + cc] = pa[i];
        }
#pragma unroll
        for (int i = 0; i < 4; i++) {
            int f = tid + i * 256;
            int r = f >> 3, cc = (f & 7) * 4;
            *(ushort4*)&Bs[r * 40 + cc] = pb[i];
        }
        __syncthreads();
        if (k0 + 32 < kend) { loadA(k0 + 32); loadB(k0 + 32); }
        s8 a[4], b[4];
#pragma unroll
        for (int mi = 0; mi < 4; mi++)
            a[mi] = *(const s8*)&As[(wm * 64 + mi * 16 + l16) * 40 + quad * 8];
#pragma unroll
        for (int ni = 0; ni < 4; ni++)
            b[ni] = *(const s8*)&Bs[(wn * 64 + ni * 16 + l16) * 40 + quad * 8];
#pragma unroll
        for (int mi = 0; mi < 4; mi++)
#pragma unroll
            for (int ni = 0; ni < 4; ni++)
                acc[mi][ni] = __builtin_amdgcn_mfma_f32_16x16x32_bf16(
                    a[mi], b[ni], acc[mi][ni], 0, 0, 0);
        __syncthreads();
    }
#pragma unroll
    for (int mi = 0; mi < 4; mi++) {
        int gmb = m0 + wm * 64 + mi * 16 + quad * 4;
#pragma unroll
        for (int ni = 0; ni < 4; ni++) {
            int gn = n0 + wn * 64 + ni * 16 + l16;
            if (gn < N) {
#pragma unroll
                for (int r = 0; r < 4; r++) {
                    float v = acc[mi][ni][r];
                    size_t off = (size_t)(gmb + r) * ldc + gn;
                    if (ATOMIC) {
                        atomicAdd((float*)Cptr + off, v);
                    } else {
                        if (bias) v += bias[gn];
                        if (ACT == 1) v = softplus_f(v);
                        if (OBF16) ((unsigned short*)Cptr)[off] = f2b(v);
                        else ((float*)Cptr)[off] = v;
                    }
                }
            }
        }
    }
}

__global__ __launch_bounds__(256) void g_kernel2(
    const float* __restrict__ flat,
    const float* __restrict__ gW1, const float* __restrict__ b1s,
    const float* __restrict__ w2s, const float* __restrict__ gb2,
    float* __restrict__ out) {
    __shared__ float4 wt[228];
    const int d = blockIdx.x;
    const int t = threadIdx.x;
    if (t < 227) {
        size_t o = (size_t)d * 227 + t;
        wt[t] = make_float4(gW1[o], b1s[o], w2s[o], 0.f);
    } else if (t == 227) {
        wt[227] = make_float4(0.f, 0.f, 0.f, 0.f);
    }
    __syncthreads();
    const int b0 = blockIdx.y * 512 + t;
    float x0 = flat[(size_t)b0 * 228 + d] * 1.44269504f;
    float x1 = flat[(size_t)(b0 + 256) * 228 + d] * 1.44269504f;
    const float g2 = gb2[d];
    float a0 = g2, a1 = g2;
    float4 w = wt[0];
#pragma unroll 2
    for (int h = 0; h < 227; h++) {
        float4 wn = wt[h + 1];
        float z0 = fmaf(x0, w.x, w.y);
        float z1 = fmaf(x1, w.x, w.y);
        a0 = fmaf(log2_f(1.f + exp2_f(z0)), w.z, a0);
        a1 = fmaf(log2_f(1.f + exp2_f(z1)), w.z, a1);
        w = wn;
    }
    out[(size_t)b0 * 415 + 62 + d] = sigmoid_f(a0);
    out[(size_t)(b0 + 256) * 415 + 62 + d] = sigmoid_f(a1);
}

__global__ __launch_bounds__(256) void heads_k(
    const float* __restrict__ flat, const float* __restrict__ ctx,
    const float* __restrict__ Wl, const float* __restrict__ Wsh, const float* __restrict__ Wm,
    const float* __restrict__ cWl, const float* __restrict__ cWsh, const float* __restrict__ cWm,
    float* __restrict__ out) {
    __shared__ float fl[227];
    __shared__ float cx[64];
    __shared__ float sraw[12], craw[12];
    __shared__ float lsf, lsc;
    const int b = blockIdx.x;
    const int t = threadIdx.x;
    if (t < 227) fl[t] = flat[(size_t)b * 228 + t];
    if (t < 64) cx[t] = ctx[(size_t)b * 64 + t];
    __syncthreads();
    float* ob = out + (size_t)b * 415;

    if (t < 25) {
        float a = 0.f;
        for (int k = 0; k < 227; k++) a = fmaf(fl[k], Wl[(size_t)k * 25 + t], a);
        ob[t] = a;
    } else if (t < 37) {
        int j = t - 25;
        float a = 0.f;
        for (int k = 0; k < 227; k++) a = fmaf(fl[k], Wsh[(size_t)k * 12 + j], a);
        sraw[j] = a;
    } else if (t < 62) {
        int j = t - 37;
        float a = 0.f;
        for (int k = 0; k < 227; k++) a = fmaf(fl[k], Wm[(size_t)k * 25 + j], a);
        ob[37 + j] = a;
    } else if (t >= 64 && t < 126) {
        int j2 = t - 64;
        if (j2 < 25) {
            float a = 0.f;
            for (int k = 0; k < 64; k++) a = fmaf(cx[k], cWl[(size_t)k * 25 + j2], a);
            ob[289 + j2] = a;
        } else if (j2 < 37) {
            int j = j2 - 25;
            float a = 0.f;
            for (int k = 0; k < 64; k++) a = fmaf(cx[k], cWsh[(size_t)k * 12 + j], a);
            craw[j] = a;
        } else {
            int j = j2 - 37;
            float a = 0.f;
            for (int k = 0; k < 64; k++) a = fmaf(cx[k], cWm[(size_t)k * 25 + j], a);
            ob[326 + j] = a;
        }
    } else if (t >= 128 && t < 192) {
        ob[351 + (t - 128)] = cx[t - 128];
    }
    __syncthreads();
    if (t == 0) lsf = lse12(sraw);
    if (t == 64) lsc = lse12(craw);
    __syncthreads();
    if (t < 12) ob[25 + t] = sraw[t] - lsf;
    else if (t >= 64 && t < 76) ob[314 + (t - 64)] = craw[t - 64] - lsc;
}

// ---------------------------------------------------------------------------
extern "C" void kernel_launch(void* const* d_in, const int* in_sizes, int n_in,
                              void* d_out, int out_size, void* d_ws, size_t ws_size,
                              hipStream_t stream) {
    const float* se    = (const float*)d_in[0];
    const float* pz    = (const float*)d_in[1];
    const float* Wref  = (const float*)d_in[2];
    const float* fW1   = (const float*)d_in[3];
    const float* fb1   = (const float*)d_in[4];
    const float* fW2   = (const float*)d_in[5];
    const float* fb2   = (const float*)d_in[6];
    const float* fW3   = (const float*)d_in[7];
    const float* fb3   = (const float*)d_in[8];
    const float* gW1   = (const float*)d_in[9];
    const float* gb1   = (const float*)d_in[10];
    const float* gW2   = (const float*)d_in[11];
    const float* gb2   = (const float*)d_in[12];
    const float* Wland = (const float*)d_in[13];
    const float* Wshot = (const float*)d_in[14];
    const float* Wmove = (const float*)d_in[15];
    const float* cW1   = (const float*)d_in[16];
    const float* cb1   = (const float*)d_in[17];
    const float* cW2   = (const float*)d_in[18];
    const float* cb2   = (const float*)d_in[19];
    const float* cW3   = (const float*)d_in[20];
    const float* cb3   = (const float*)d_in[21];
    const float* cWl   = (const float*)d_in[22];
    const float* cWs   = (const float*)d_in[23];
    const float* cWm   = (const float*)d_in[24];
    float* out = (float*)d_out;
    const int M = 4096;

    char* p = (char*)d_ws;
    auto alloc = [&](size_t bytes) {
        char* r = p;
        p += (bytes + 255) & ~(size_t)255;
        return r;
    };
    // ---- common base ----
    unsigned short* WcatT = (unsigned short*)alloc((size_t)256 * 5792 * 2);
    unsigned short* cW1T  = (unsigned short*)alloc((size_t)1024 * 64 * 2);
    unsigned short* cW2T  = (unsigned short*)alloc((size_t)1024 * 1024 * 2);
    unsigned short* cW3T  = (unsigned short*)alloc((size_t)128 * 1024 * 2);
    unsigned short* fW1T  = (unsigned short*)alloc((size_t)1024 * 256 * 2);
    unsigned short* fW2T  = (unsigned short*)alloc((size_t)1024 * 1024 * 2);
    unsigned short* fW3T  = (unsigned short*)alloc((size_t)256 * 1024 * 2);
    float* fin  = (float*)alloc((size_t)M * 228 * 4);   // fallback target; full: partial span base
    float* flat = (float*)alloc((size_t)M * 228 * 4);
    float* ctxb = (float*)alloc((size_t)M * 64 * 4);
    unsigned short* h2b  = (unsigned short*)alloc((size_t)M * 1024 * 2);  // c-chain h2
    unsigned short* h1fb = (unsigned short*)alloc((size_t)M * 1024 * 2);  // c-chain h1
    float* b1s = (float*)alloc((size_t)227 * 227 * 4);
    float* w2s = (float*)alloc((size_t)227 * 227 * 4);

    size_t base_used = (size_t)(p - (char*)d_ws);
    size_t full_extra = (size_t)M * 64 * 2            // pzb
                      + (size_t)M * 256 * 2           // finb
                      + (size_t)M * 5792 * 2          // region
                      + (size_t)128 * 320 * 2 + 1024; // WhcT
    const bool full = (base_used + full_extra + 65536) <= ws_size;

    if (full) {
        unsigned short* pzb  = (unsigned short*)alloc((size_t)M * 64 * 2);
        unsigned short* finb = (unsigned short*)alloc((size_t)M * 256 * 2);
        char* region = alloc((size_t)M * 5792 * 2);                     // 45.25 MiB
        unsigned short* WhcT = (unsigned short*)alloc((size_t)128 * 320 * 2);
        unsigned short* Acat = (unsigned short*)region;
        float* part_enc = fin;  // spans fin..h1fb (24.1 MiB >= 6*3.56 MiB)
        // after encoder, Acat dead -> region layout:
        unsigned short* h2fb   = (unsigned short*)region;                            // [0, 8 MiB)
        float* part_c3         = (float*)(region + (size_t)8 * 1024 * 1024);         // 8 MiB
        unsigned short* h1f    = (unsigned short*)(region + (size_t)16 * 1024 * 1024);
        float* part_f3         = (float*)(region + (size_t)24 * 1024 * 1024);        // 14.25 MiB
        unsigned short* Ah     = (unsigned short*)(region + (size_t)41 * 1024 * 1024);
        unsigned short* h1c = h1fb;
        unsigned short* h2c = h2b;

        // 1. all prep in one launch
        prep_all_k<<<dim3(17874), 256, 0, stream>>>(
            cW1, cW2, cW3, fW1, fW2, fW3, cW1T, cW2T, cW3T, fW1T, fW2T, fW3T,
            Wref, WcatT, pz, pzb, gb1, gW2, b1s, w2s,
            Wland, Wshot, Wmove, cWl, cWs, cWm, WhcT, se, Acat);

        // 2. encoder split-K partials (z=6)
        gemm_dma<2, 0, false><<<dim3(2, 32, 6), 256, 0, stream>>>(
            Acat, 5792, WcatT, 5792, nullptr, part_enc, 228, 227, 5792, 992);
        // 3. reduce -> finb bf16
        red_enc4<<<dim3(1, 1024), 256, 0, stream>>>(part_enc, finb);

        // 4. c1 & f1 dual
        gemm_dualg<<<dim3(8, 32, 2), 256, 0, stream>>>(
            pzb, 64, 64, finb, 256, 256, cW1T, 64, fW1T, 256, cb1, fb1, h1c, h1f);
        // 5. c2 & f2 dual
        gemm_dualg<<<dim3(8, 32, 2), 256, 0, stream>>>(
            h1c, 1024, 1024, h1f, 1024, 1024, cW2T, 1024, fW2T, 1024, cb2, fb2, h2c, h2fb);

        // 6. c3 + f3 partials, 7. fused reduce
        part_cf3_k<<<dim3(2, 32, 12), 256, 0, stream>>>(
            h2c, cW3T, h2fb, fW3T, part_c3, part_f3);
        red_cf3_k<<<dim3(1280), 256, 0, stream>>>(
            part_c3, cb3, ctxb, part_f3, fb3, flat);

        // 8. g-net || Ah concat (one launch, complementary pipes)
        tail_k<<<dim3(5912), 256, 0, stream>>>(
            flat, gW1, b1s, w2s, gb2, ctxb, Ah, out);

        // 9. heads GEMM with fused final epilogue
        gemm_heads_k<<<dim3(32), 256, 0, stream>>>(Ah, WhcT, ctxb, out);
    } else {
        // -------- fallback: r6 structure (known-good) --------
        const dim3 tb(32, 8);
        transpose_w<<<dim3(32, 2),  tb, 0, stream>>>(cW1, cW1T, 64, 1024, 64, 1024);
        transpose_w<<<dim3(32, 32), tb, 0, stream>>>(cW2, cW2T, 1024, 1024, 1024, 1024);
        transpose_w<<<dim3(4, 32),  tb, 0, stream>>>(cW3, cW3T, 1024, 64, 1024, 128);
        transpose_w<<<dim3(32, 8),  tb, 0, stream>>>(fW1, fW1T, 227, 1024, 256, 1024);
        transpose_w<<<dim3(32, 32), tb, 0, stream>>>(fW2, fW2T, 1024, 1024, 1024, 1024);
        transpose_w<<<dim3(8, 32),  tb, 0, stream>>>(fW3, fW3T, 1024, 227, 1024, 256);
        wcat_t<<<dim3(8, 181), tb, 0, stream>>>(Wref, WcatT);
        gscale_k<<<dim3(202), 256, 0, stream>>>(gb1, gW2, b1s, w2s);
        fillb_k<<<dim3(1, M), 256, 0, stream>>>(fin, nullptr, 228, 0);
        fillb_k<<<dim3(1, M), 256, 0, stream>>>(flat, fb3, 228, 227);
        fillb_k<<<dim3(1, M), 256, 0, stream>>>(ctxb, cb3, 64, 64);
        unsigned short* h1 = h1fb;
        gemm_mfma<0, 1, false, true><<<dim3(8, 32, 1), 256, 0, stream>>>(
            pz, 64, nullptr, cW1T, 64, cb1, h1, 1024, M, 1024, 64, 64);
        gemm_mfma<1, 1, false, true><<<dim3(8, 32, 1), 256, 0, stream>>>(
            h1, 1024, nullptr, cW2T, 1024, cb2, h2b, 1024, M, 1024, 1024, 1024);
        gemm_mfma<1, 0, true, false><<<dim3(1, 32, 8), 256, 0, stream>>>(
            h2b, 1024, nullptr, cW3T, 1024, nullptr, ctxb, 64, M, 64, 1024, 128);
        gemm_mfma<2, 0, true, false><<<dim3(2, 32, 8), 256, 0, stream>>>(
            se, 5705, pz, WcatT, 5792, nullptr, fin, 228, M, 227, 5769, 736);
        gemm_mfma<0, 1, false, true><<<dim3(8, 32, 1), 256, 0, stream>>>(
            fin, 228, nullptr, fW1T, 256, fb1, h1, 1024, M, 1024, 227, 227);
        gemm_mfma<1, 1, false, true><<<dim3(8, 32, 1), 256, 0, stream>>>(
            h1, 1024, nullptr, fW2T, 1024, fb2, h2b, 1024, M, 1024, 1024, 1024);
        gemm_mfma<1, 0, true, false><<<dim3(2, 32, 8), 256, 0, stream>>>(
            h2b, 1024, nullptr, fW3T, 1024, nullptr, flat, 228, M, 227, 1024, 128);
        heads_k<<<dim3(4096), 256, 0, stream>>>(flat, ctxb, Wland, Wshot, Wmove,
                                                cWl, cWs, cWm, out);
        g_kernel2<<<dim3(227, 8), 256, 0, stream>>>(flat, gW1, b1s, w2s, gb2, out);
    }
}